// Round 8
// baseline (1093.745 us; speedup 1.0000x reference)
//
#include <hip/hip_runtime.h>
#include <math.h>

#define QS 1024
#define BSZ 4
#define NH 16
#define RL 2048

typedef __attribute__((ext_vector_type(8))) __bf16 bf16x8;
typedef __attribute__((ext_vector_type(16))) float f32x16;
typedef __attribute__((ext_vector_type(4))) float f32x4;

union BV8 { bf16x8 v; uint4 u; __bf16 e[8]; unsigned w[4]; };

// byte offset in a [rows][64 bf16] tile, 128B rows, blk-XOR swizzle
__device__ __forceinline__ int swzb(int row, int blk) {
  return row * 128 + (((blk ^ row) & 7) << 4);
}

typedef __attribute__((address_space(3))) unsigned int lds_u32;
typedef __attribute__((address_space(1))) const unsigned int glb_u32;
__device__ __forceinline__ void gld16(const void* g, void* l) {
  __builtin_amdgcn_global_load_lds((glb_u32*)g, (lds_u32*)l, 16, 0, 0);
}

// ---------------- f32 -> bf16 convert ----------------
__global__ __launch_bounds__(256) void cvt_bf16_k(const float* __restrict__ in,
                                                  __bf16* __restrict__ out, int n) {
  int i = blockIdx.x * 1024 + threadIdx.x * 4;
  if (i + 3 < n) {
    float4 v = *(const float4*)(in + i);
    union { __bf16 b[4]; unsigned long long u; } r;
    r.b[0] = (__bf16)v.x; r.b[1] = (__bf16)v.y;
    r.b[2] = (__bf16)v.z; r.b[3] = (__bf16)v.w;
    *(unsigned long long*)(out + i) = r.u;
  }
}

// ---------------- W[k][n] f32 -> WT[n][k] bf16 ----------------
__global__ __launch_bounds__(256) void wtrans_k(const float* __restrict__ W,
                                                __bf16* __restrict__ WT) {
  __shared__ float tile[64][65];
  int k0 = blockIdx.x * 64, n0 = blockIdx.y * 64;
  int t = threadIdx.x, r = t >> 4, c4 = (t & 15) * 4;
#pragma unroll
  for (int p = 0; p < 4; ++p) {
    float4 v = *(const float4*)(W + (size_t)(k0 + r + 16 * p) * 1024 + n0 + c4);
    *(float4*)&tile[r + 16 * p][c4] = v;
  }
  __syncthreads();
#pragma unroll
  for (int p = 0; p < 4; ++p) {
    int nr = r + 16 * p;
    union { __bf16 b[4]; unsigned long long u; } o;
#pragma unroll
    for (int i = 0; i < 4; ++i) o.b[i] = (__bf16)tile[c4 + i][nr];
    *(unsigned long long*)(WT + (size_t)(n0 + nr) * 1024 + k0 + c4) = o.u;
  }
}

// ------- pack masks to bitfields: mbits[tn(z)][b][j][1024 i-bits] -------
__global__ __launch_bounds__(256) void packbits_k(const float* __restrict__ mh,
                                                  const float* __restrict__ mg,
                                                  unsigned int* __restrict__ mbits) {
  __shared__ unsigned char nib[2][16][64];
  const int t = threadIdx.x;
  const int i0b = blockIdx.x * 64;
  const int jb0 = blockIdx.y * 64;
  const float* srcs[2] = {mh, mg};
#pragma unroll
  for (int tn = 0; tn < 2; ++tn) {
    const float* in = srcs[tn];
#pragma unroll
    for (int p = 0; p < 4; ++p) {
      int item = t + 256 * p;
      int iloc = item >> 4, jbq = item & 15;
      float4 v = *(const float4*)(in + (size_t)(i0b + iloc) * 4096 + jb0 + jbq * 4);
      unsigned char nb = (v.x > 0.5f ? 1 : 0) | (v.y > 0.5f ? 2 : 0) |
                         (v.z > 0.5f ? 4 : 0) | (v.w > 0.5f ? 8 : 0);
      nib[tn][jbq][iloc] = nb;
    }
  }
  __syncthreads();
  {
    int tn = t >> 7, rem = t & 127;
    int jbl = rem >> 1, dw = rem & 1;
    int jbq = jbl >> 2, e = jbl & 3;
    uint4 u0 = *(uint4*)&nib[tn][jbq][32 * dw];
    uint4 u1 = *(uint4*)&nib[tn][jbq][32 * dw + 16];
    unsigned d[8] = {u0.x, u0.y, u0.z, u0.w, u1.x, u1.y, u1.z, u1.w};
    unsigned out = 0;
#pragma unroll
    for (int c = 0; c < 8; ++c) {
      unsigned bits = (d[c] >> e) & 0x01010101u;
      unsigned nv = ((bits * 0x01020408u) >> 24) & 0xFu;
      out |= nv << (4 * c);
    }
    int jb = jb0 + jbl;
    int b = jb & 3, j = jb >> 2;
    mbits[(size_t)(((tn * 4 + b) * 1024 + j)) * 32 + (i0b >> 5) + dw] = out;
  }
}

// ------- segv[b][j] = seg-bit of token j -------
__global__ __launch_bounds__(256) void segv_k(const float* __restrict__ seg,
                                              unsigned char* __restrict__ segv) {
  int id = blockIdx.x * 256 + threadIdx.x;
  if (id < 4096) {
    int b = id >> 10, j = id & 1023;
    segv[b * 1024 + j] = (seg[(size_t)(j * 4 + b) * 2 + 1] > 0.5f) ? 1 : 0;
  }
}

// ---------------- bf16 MFMA GEMM: C[M][1024] = A[M][1024] * BT^T ----------------
template <bool OUT_BF16>
__global__ __launch_bounds__(256) void gemm_mfma(const __bf16* __restrict__ A,
                                                 const __bf16* __restrict__ BT,
                                                 void* __restrict__ Cout) {
  alignas(16) __shared__ __bf16 sA[128 * 64];
  alignas(16) __shared__ __bf16 sB[128 * 64];
  const int t = threadIdx.x;
  const int lane = t & 63, wave = t >> 6;
  // XCD remap: each XCD owns a contiguous M-stripe across all N (A fetched once)
  const int lin = blockIdx.y * 8 + blockIdx.x;
  const int xcd = lin & 7, l = lin >> 3;
  const int n0 = (l & 7) * 128;
  const size_t m0 = (size_t)(xcd * (gridDim.y >> 3) + (l >> 3)) * 128;
  const int wm = (wave >> 1) * 64, wn = (wave & 1) * 64;

  f32x16 acc[2][2];
#pragma unroll
  for (int a = 0; a < 2; ++a)
#pragma unroll
    for (int b = 0; b < 2; ++b)
#pragma unroll
      for (int i = 0; i < 16; ++i) acc[a][b][i] = 0.f;

  for (int k0 = 0; k0 < 1024; k0 += 64) {
    __syncthreads();
#pragma unroll
    for (int p = 0; p < 4; ++p) {
      int idx = t + 256 * p;
      int row = idx >> 3, blk = idx & 7;
      int sblk = (blk ^ (row & 7)) * 8;
      gld16(A + (m0 + row) * 1024 + k0 + sblk, (char*)sA + idx * 16);
      gld16(BT + (size_t)(n0 + row) * 1024 + k0 + sblk, (char*)sB + idx * 16);
    }
    __syncthreads();
#pragma unroll
    for (int kk = 0; kk < 4; ++kk) {
      int blk = 2 * kk + (lane >> 5);
      bf16x8 af[2], bfr[2];
#pragma unroll
      for (int mi = 0; mi < 2; ++mi)
        af[mi] = *(bf16x8*)((char*)sA + swzb(wm + mi * 32 + (lane & 31), blk));
#pragma unroll
      for (int ni = 0; ni < 2; ++ni)
        bfr[ni] = *(bf16x8*)((char*)sB + swzb(wn + ni * 32 + (lane & 31), blk));
#pragma unroll
      for (int mi = 0; mi < 2; ++mi)
#pragma unroll
        for (int ni = 0; ni < 2; ++ni)
          acc[mi][ni] = __builtin_amdgcn_mfma_f32_32x32x16_bf16(
              af[mi], bfr[ni], acc[mi][ni], 0, 0, 0);
    }
  }
#pragma unroll
  for (int mi = 0; mi < 2; ++mi)
#pragma unroll
    for (int ni = 0; ni < 2; ++ni)
#pragma unroll
      for (int rg = 0; rg < 16; ++rg) {
        int row = wm + mi * 32 + (rg & 3) + 8 * (rg >> 2) + 4 * (lane >> 5);
        int col = wn + ni * 32 + (lane & 31);
        float v = acc[mi][ni][rg];
        if (OUT_BF16)
          ((__bf16*)Cout)[(m0 + row) * 1024 + n0 + col] = (__bf16)v;
        else
          ((float*)Cout)[(m0 + row) * 1024 + n0 + col] = v;
      }
}

// ---------------- V transpose: vhb [tok][(b,n,d)] -> vtb [(b,n,d)][tok] ----------------
__global__ __launch_bounds__(256) void vtrans_k(const __bf16* __restrict__ vhb,
                                                __bf16* __restrict__ vtb) {
  alignas(16) __shared__ __bf16 st[64 * 128];
  const int t = threadIdx.x;
  const int tok0 = blockIdx.x * 128;
  const int bn = blockIdx.y;
  const int b = bn >> 4, n = bn & 15;
#pragma unroll
  for (int p = 0; p < 4; ++p) {
    int item = t + 256 * p;
    int tok = item >> 3, c8 = item & 7;
    BV8 v;
    v.u = *(const uint4*)(vhb + ((size_t)((tok0 + tok) * 4 + b)) * 1024 + n * 64 + c8 * 8);
#pragma unroll
    for (int e = 0; e < 8; ++e) {
      int d = c8 * 8 + e;
      *(__bf16*)((char*)st + d * 256 + ((2 * tok) ^ (((d >> 3) & 7) << 4))) = v.e[e];
    }
  }
  __syncthreads();
#pragma unroll
  for (int p = 0; p < 4; ++p) {
    int item = t + 256 * p;
    int d = item >> 4, tc = (item & 15) * 8;
    uint4 v = *(uint4*)((char*)st + d * 256 + ((2 * tc) ^ (((d >> 3) & 7) << 4)));
    *(uint4*)(vtb + ((size_t)(bn * 64 + d)) * 1024 + tok0 + tc) = v;
  }
}

// ---------------- fused relative attention v4: counted-vmcnt pipeline ----------------
__global__ __launch_bounds__(256, 3) void attn4(
    const __bf16* __restrict__ qpb, const __bf16* __restrict__ kb,
    const __bf16* __restrict__ vtb, const __bf16* __restrict__ krb,
    const unsigned int* __restrict__ mbits, const unsigned char* __restrict__ segv,
    const float* __restrict__ se, const float* __restrict__ rwb,
    const float* __restrict__ rrb, const float* __restrict__ rsb,
    __bf16* __restrict__ av) {
  const int t = threadIdx.x;
  const int lane = t & 63, wave = t >> 6;
  const int hlf = lane >> 5, ln31 = lane & 31;
  const int qh = wave >> 1, kh = wave & 1;

  // XCD-aware 1D decode: 8 heads of one batch per XCD
  const int bid = blockIdx.x;
  const int xcd = bid & 7, idx0 = bid >> 3;
  const int bn = xcd * 8 + (idx0 & 7);
  const int i0 = ((idx0 >> 3) & 15) * 64;
  const int z = idx0 >> 7;
  const int b = bn >> 4, n = bn & 15;

  alignas(16) __shared__ __bf16 ring[8 * 32 * 64];   // 32KB Kr sliding window
  alignas(16) __shared__ __bf16 sp[2][2][32 * 64];   // 16KB P double-buffered
  __shared__ float sl[4][2][16];

  const int wpro = 960 - i0;  // ring prologue base (>=0, mult of 32)
  // ---- prologue: stage ring rows [wpro, wpro+127] (4 gld16, oldest VMEM) ----
#pragma unroll
  for (int p = 0; p < 4; ++p) {
    int item = t + 256 * p;
    int wl = item >> 3, blk = item & 7;
    int w = wpro + wl;
    int wc = min(w, 2047);
    gld16(krb + ((size_t)(wc * 4 + b)) * 1024 + n * 64 + ((blk ^ (w & 7)) << 3),
          (char*)ring + ((w >> 5) & 7) * 4096 + (w & 31) * 128 + blk * 16);
  }
  __builtin_amdgcn_sched_barrier(0);

  // ---- Q fragments (+biases), alpha/beta for segment fold ----
  const size_t qbase =
      ((size_t)((z * 1024 + i0 + 32 * qh + ln31) * 4 + b)) * 1024 + n * 64;
  bf16x8 qw[4], qr[4];
  float e0 = 0.f, e1 = 0.f;
#pragma unroll
  for (int kk = 0; kk < 4; ++kk) {
    BV8 raw;
    raw.u = *(const uint4*)(qpb + qbase + 16 * kk + 8 * hlf);
    int d0 = 16 * kk + 8 * hlf;
    float4 w0 = *(const float4*)(rwb + n * 64 + d0);
    float4 w1 = *(const float4*)(rwb + n * 64 + d0 + 4);
    float4 r0 = *(const float4*)(rrb + n * 64 + d0);
    float4 r1 = *(const float4*)(rrb + n * 64 + d0 + 4);
    float4 sb0 = *(const float4*)(rsb + n * 64 + d0);
    float4 sb1 = *(const float4*)(rsb + n * 64 + d0 + 4);
    float4 ea0 = *(const float4*)(se + n * 64 + d0);
    float4 ea1 = *(const float4*)(se + n * 64 + d0 + 4);
    float4 eb0 = *(const float4*)(se + 1024 + n * 64 + d0);
    float4 eb1 = *(const float4*)(se + 1024 + n * 64 + d0 + 4);
    float wv[8] = {w0.x, w0.y, w0.z, w0.w, w1.x, w1.y, w1.z, w1.w};
    float rv[8] = {r0.x, r0.y, r0.z, r0.w, r1.x, r1.y, r1.z, r1.w};
    float sv_[8] = {sb0.x, sb0.y, sb0.z, sb0.w, sb1.x, sb1.y, sb1.z, sb1.w};
    float ev0[8] = {ea0.x, ea0.y, ea0.z, ea0.w, ea1.x, ea1.y, ea1.z, ea1.w};
    float ev1[8] = {eb0.x, eb0.y, eb0.z, eb0.w, eb1.x, eb1.y, eb1.z, eb1.w};
    BV8 qwv, qrv;
#pragma unroll
    for (int i = 0; i < 8; ++i) {
      float f = (float)raw.e[i];
      qwv.e[i] = (__bf16)(f + wv[i]);
      qrv.e[i] = (__bf16)(f + rv[i]);
      float fs = f + sv_[i];
      e0 += fs * ev0[i];
      e1 += fs * ev1[i];
    }
    qw[kk] = qwv.v;
    qr[kk] = qrv.v;
  }
  e0 += __shfl_xor(e0, 32);
  e1 += __shfl_xor(e1, 32);
  float si = (float)segv[b * 1024 + i0 + 32 * qh + ln31];
  float alpha = e0 + (e1 - e0) * si;
  float beta = (e1 - e0) * (1.f - 2.f * si);
  bf16x8 augA;
  {
    BV8 aa;
    aa.w[0] = aa.w[1] = aa.w[2] = aa.w[3] = 0;
    if (!hlf) {
      union { __bf16 b2[2]; unsigned u; } w2;
      w2.b2[0] = (__bf16)alpha;
      w2.b2[1] = (__bf16)beta;
      aa.w[0] = w2.u;
    }
    augA = aa.v;
  }

  f32x16 oacc, colsum;
#pragma unroll
  for (int i = 0; i < 16; ++i) { oacc[i] = 0.f; colsum[i] = 0.f; }

  const unsigned char* segp = segv + b * 1024;
  const __bf16* kbase = kb + ((size_t)((32 * kh + ln31) * 4 + b)) * 1024 + n * 64 + 8 * hlf;
  const __bf16* vbase = vtb + ((size_t)(bn * 64 + 32 * kh + ln31)) * 1024 + 8 * hlf;
  const size_t mbase = (size_t)((z * 4 + b) * 1024 + 32 * kh + ln31) * 32 + (i0 >> 5) + qh;

  // ---- prefetch iter 0: exactly 10 trailing VMEM ops ----
  bf16x8 kf[4], vf[4];
#pragma unroll
  for (int kk = 0; kk < 4; ++kk) {
    kf[kk] = *(const bf16x8*)(kbase + 16 * kk);
    vf[kk] = *(const bf16x8*)(vbase + 16 * kk);
  }
  unsigned praw = mbits[mbase];
  unsigned sj = segp[32 * kh + ln31];

  asm volatile("s_waitcnt vmcnt(10)\n\ts_barrier" ::: "memory");
  __builtin_amdgcn_sched_barrier(0);

  for (int jt = 0; jt < 16; ++jt) {
    const int J0 = 64 * jt;
    // ---- (A) stage next 2 ring slots (these 2 gld16 stay the oldest) ----
    if (jt < 15) {
      int wsb = wpro + 128 + 64 * jt;
#pragma unroll
      for (int p = 0; p < 2; ++p) {
        int item = t + 256 * p;
        int wl = item >> 3, blk = item & 7;
        int w = wsb + wl;
        int wc = min(w, 2047);
        gld16(krb + ((size_t)(wc * 4 + b)) * 1024 + n * 64 + ((blk ^ (w & 7)) << 3),
              (char*)ring + ((w >> 5) & 7) * 4096 + (w & 31) * 128 + blk * 16);
      }
    }
    __builtin_amdgcn_sched_barrier(0);

    // ---- (B) BD (ring) + AC (prefetched kf) + segment fold ----
    bf16x8 augB;
    {
      BV8 bb2;
      bb2.w[0] = hlf ? 0u : (0x3F80u | (sj * 0x3F800000u));
      bb2.w[1] = bb2.w[2] = bb2.w[3] = 0;
      augB = bb2.v;
    }
    const int base0 = J0 + 32 * (kh - qh) + 993 - i0;
    f32x16 bd[2];
    f32x16 ac;
#pragma unroll
    for (int i = 0; i < 16; ++i) { bd[0][i] = 0.f; bd[1][i] = 0.f; ac[i] = 0.f; }
    __builtin_amdgcn_s_setprio(1);
#pragma unroll
    for (int tt = 0; tt < 2; ++tt) {
      int w = base0 + 32 * tt + ln31;
      int rbyte = ((w >> 5) & 7) * 4096 + (w & 31) * 128;
      int wx = (w & 7) << 4;
#pragma unroll
      for (int kk = 0; kk < 4; ++kk) {
        bf16x8 bbr = *(const bf16x8*)((char*)ring + rbyte + (((2 * kk + hlf) << 4) ^ wx));
        bd[tt] = __builtin_amdgcn_mfma_f32_32x32x16_bf16(qr[kk], bbr, bd[tt], 0, 0, 0);
      }
    }
#pragma unroll
    for (int kk = 0; kk < 4; ++kk)
      ac = __builtin_amdgcn_mfma_f32_32x32x16_bf16(qw[kk], kf[kk], ac, 0, 0, 0);
    ac = __builtin_amdgcn_mfma_f32_32x32x16_bf16(augA, augB, ac, 0, 0, 0);
    __builtin_amdgcn_s_setprio(0);

    // ---- (C) prefetch jt+1: exactly 10 VMEM ops ----
    const int J0n = (jt < 15) ? J0 + 64 : J0;
    bf16x8 kfn[4], vfn[4];
#pragma unroll
    for (int kk = 0; kk < 4; ++kk) {
      kfn[kk] = *(const bf16x8*)(kbase + (size_t)J0n * 4096 + 16 * kk);
      vfn[kk] = *(const bf16x8*)(vbase + J0n + 16 * kk);
    }
    unsigned prawn = mbits[mbase + (size_t)J0n * 32];
    unsigned sjn = segp[J0n + 32 * kh + ln31];

    // ---- (D) realign BD + score + P write (buffer jt&1) ----
    char* spw = (char*)&sp[jt & 1][qh][0];
#pragma unroll
    for (int rg = 0; rg < 16; ++rg) {
      int q_ = (rg & 3) + 8 * (rg >> 2) + 4 * hlf;
      int jsrc = (ln31 + q_ + 1) & 31;
      float selv = (jsrc > q_) ? bd[1][rg] : bd[0][rg];
      int addr = ((lane & 32) | ((ln31 + 31 - q_) & 31)) << 2;
      float bdr = __int_as_float(
          __builtin_amdgcn_ds_bpermute(addr, __float_as_int(selv)));
      float s = (ac[rg] + bdr) * 0.18033688f;  // 0.125*log2(e)
      float p = __builtin_amdgcn_exp2f(s);
      int sh = (rg & 3) + 8 * (rg >> 2);
      p = ((praw >> (hlf * 4 + sh)) & 1) ? 0.f : p;
      colsum[rg] += p;
      *(__bf16*)(spw + q_ * 128 + ((2 * (32 * kh + ln31)) ^ ((q_ & 7) << 4))) =
          (__bf16)p;
    }

    // ---- (E) single counted barrier: ring complete, prefetches in flight ----
    asm volatile("s_waitcnt vmcnt(10) lgkmcnt(0)\n\ts_barrier" ::: "memory");
    __builtin_amdgcn_sched_barrier(0);

    // ---- (F) PV ----
    __builtin_amdgcn_s_setprio(1);
#pragma unroll
    for (int kk = 0; kk < 4; ++kk) {
      bf16x8 pa = *(const bf16x8*)(
          spw + ln31 * 128 + ((32 * kk + 16 * hlf) ^ ((ln31 & 7) << 4)));
      oacc = __builtin_amdgcn_mfma_f32_32x32x16_bf16(pa, vf[kk], oacc, 0, 0, 0);
    }
    __builtin_amdgcn_s_setprio(0);

    // ---- (G) rotate prefetches ----
#pragma unroll
    for (int kk = 0; kk < 4; ++kk) { kf[kk] = kfn[kk]; vf[kk] = vfn[kk]; }
    praw = prawn;
    sj = sjn;
  }

  // ---- epilogue: l reduce + merge + scale + store ----
#pragma unroll
  for (int m = 1; m <= 16; m <<= 1)
#pragma unroll
    for (int rg = 0; rg < 16; ++rg) colsum[rg] += __shfl_xor(colsum[rg], m);
  __syncthreads();
  if (ln31 == 0) {
#pragma unroll
    for (int rg = 0; rg < 16; ++rg) sl[wave][hlf][rg] = colsum[rg];
  }
  __syncthreads();
#pragma unroll
  for (int rg = 0; rg < 16; ++rg) {
    float l = sl[2 * qh][hlf][rg] + sl[2 * qh + 1][hlf][rg];
    float rl = __fdividef(1.f, l);
    int qrow = 32 * qh + (rg & 3) + 8 * (rg >> 2) + 4 * hlf;
    av[((size_t)((z * 1024 + i0 + qrow) * 4 + b)) * 1024 + n * 64 + 32 * kh + ln31] =
        (__bf16)(oacc[rg] * rl);
  }
}

// ------------- residual add + LayerNorm (in-place on io) -------------
__global__ __launch_bounds__(256) void add_ln(float* __restrict__ io,
                                              const float* __restrict__ h,
                                              const float* __restrict__ g,
                                              const float* __restrict__ gam,
                                              const float* __restrict__ bet) {
  const size_t row = blockIdx.x;
  float* o = io + row * 1024;
  const float* x = (row < 4096) ? (h + row * 1024) : (g + (row - 4096) * 1024);
  const int t = threadIdx.x;
  float v[4];
  float s1 = 0.f, s2 = 0.f;
#pragma unroll
  for (int k = 0; k < 4; ++k) {
    int idx = t + 256 * k;
    v[k] = o[idx] + x[idx];
    s1 += v[k];
    s2 += v[k] * v[k];
  }
#pragma unroll
  for (int off = 32; off >= 1; off >>= 1) {
    s1 += __shfl_xor(s1, off);
    s2 += __shfl_xor(s2, off);
  }
  __shared__ float r1[4], r2[4];
  if ((t & 63) == 0) { r1[t >> 6] = s1; r2[t >> 6] = s2; }
  __syncthreads();
  s1 = r1[0] + r1[1] + r1[2] + r1[3];
  s2 = r2[0] + r2[1] + r2[2] + r2[3];
  float mean = s1 * (1.f / 1024.f);
  float var = s2 * (1.f / 1024.f) - mean * mean;
  float rstd = rsqrtf(fmaxf(var, 0.f) + 1e-12f);
#pragma unroll
  for (int k = 0; k < 4; ++k) {
    int idx = t + 256 * k;
    o[idx] = (v[k] - mean) * rstd * gam[idx] + bet[idx];
  }
}

extern "C" void kernel_launch(void* const* d_in, const int* in_sizes, int n_in,
                              void* d_out, int out_size, void* d_ws,
                              size_t ws_size, hipStream_t stream) {
  const float* h = (const float*)d_in[0];
  const float* g = (const float*)d_in[1];
  const float* mh = (const float*)d_in[2];
  const float* mg = (const float*)d_in[3];
  const float* r = (const float*)d_in[4];
  const float* seg = (const float*)d_in[5];
  const float* q_w = (const float*)d_in[6];
  const float* k_w = (const float*)d_in[7];
  const float* v_w = (const float*)d_in[8];
  const float* o_w = (const float*)d_in[9];
  const float* r_w = (const float*)d_in[10];
  const float* rrb = (const float*)d_in[11];
  const float* rsb = (const float*)d_in[12];
  const float* rwb = (const float*)d_in[13];
  const float* se = (const float*)d_in[14];
  const float* gam = (const float*)d_in[15];
  const float* bet = (const float*)d_in[16];
  float* out = (float*)d_out;

  // ---- ws layout ----
  char* w = (char*)d_ws;
  __bf16* hgb = (__bf16*)w;                 // 16MB [8192][1024]
  __bf16* vtb = (__bf16*)w;                 // aliases hgb (dead after q-GEMM)
  w += (size_t)16 << 20;
  __bf16* rb = (__bf16*)w;                  // 16MB
  __bf16* avb = (__bf16*)w;                 // aliases rb (dead after r-GEMM)
  w += (size_t)16 << 20;
  __bf16* qwt = (__bf16*)w; w += (size_t)2 << 20;
  __bf16* kwt = (__bf16*)w; w += (size_t)2 << 20;
  __bf16* vwt = (__bf16*)w; w += (size_t)2 << 20;
  __bf16* rwt = (__bf16*)w; w += (size_t)2 << 20;
  __bf16* owt = (__bf16*)w; w += (size_t)2 << 20;
  __bf16* qpb = (__bf16*)w; w += (size_t)16 << 20;  // [8192][1024]
  __bf16* khb = (__bf16*)w; w += (size_t)8 << 20;
  __bf16* vhb = (__bf16*)w; w += (size_t)8 << 20;
  __bf16* krb = (__bf16*)w; w += (size_t)16 << 20;
  unsigned int* mbits = (unsigned int*)w; w += (size_t)1 << 20;
  unsigned char* segvb = (unsigned char*)w; w += 4096;

  dim3 blk(256);

  cvt_bf16_k<<<4096, blk, 0, stream>>>(h, hgb, 4194304);
  cvt_bf16_k<<<4096, blk, 0, stream>>>(g, hgb + 4194304, 4194304);
  cvt_bf16_k<<<8192, blk, 0, stream>>>(r, rb, 8388608);
  cvt_bf16_k<<<1024, blk, 0, stream>>>(o_w, owt, 1048576);
  wtrans_k<<<dim3(16, 16), blk, 0, stream>>>(q_w, qwt);
  wtrans_k<<<dim3(16, 16), blk, 0, stream>>>(k_w, kwt);
  wtrans_k<<<dim3(16, 16), blk, 0, stream>>>(v_w, vwt);
  wtrans_k<<<dim3(16, 16), blk, 0, stream>>>(r_w, rwt);
  packbits_k<<<dim3(16, 64), blk, 0, stream>>>(mh, mg, mbits);
  segv_k<<<16, blk, 0, stream>>>(seg, segvb);

  gemm_mfma<true><<<dim3(8, 32), blk, 0, stream>>>(hgb, kwt, khb);
  gemm_mfma<true><<<dim3(8, 32), blk, 0, stream>>>(hgb, vwt, vhb);
  gemm_mfma<true><<<dim3(8, 64), blk, 0, stream>>>(rb, rwt, krb);
  gemm_mfma<true><<<dim3(8, 64), blk, 0, stream>>>(hgb, qwt, qpb);  // hgb dead after
  vtrans_k<<<dim3(8, 64), blk, 0, stream>>>(vhb, vtb);

  attn4<<<2048, blk, 0, stream>>>(qpb, khb, vtb, krb, mbits, segvb, se, rwb,
                                  rrb, rsb, avb);

  gemm_mfma<false><<<dim3(8, 64), blk, 0, stream>>>(avb, owt, out);
  add_ln<<<8192, blk, 0, stream>>>(out, h, g, gam, bet);
}

// Round 9
// 841.985 us; speedup vs baseline: 1.2990x; 1.2990x over previous
//
#include <hip/hip_runtime.h>
#include <math.h>

#define QS 1024
#define BSZ 4
#define NH 16
#define RL 2048

typedef __attribute__((ext_vector_type(8))) __bf16 bf16x8;
typedef __attribute__((ext_vector_type(16))) float f32x16;
typedef __attribute__((ext_vector_type(4))) float f32x4;

union BV8 { bf16x8 v; uint4 u; __bf16 e[8]; unsigned w[4]; };

// byte offset in a [rows][64 bf16] tile, 128B rows, blk-XOR swizzle
__device__ __forceinline__ int swzb(int row, int blk) {
  return row * 128 + (((blk ^ row) & 7) << 4);
}

typedef __attribute__((address_space(3))) unsigned int lds_u32;
typedef __attribute__((address_space(1))) const unsigned int glb_u32;
__device__ __forceinline__ void gld16(const void* g, void* l) {
  __builtin_amdgcn_global_load_lds((glb_u32*)g, (lds_u32*)l, 16, 0, 0);
}

// ---------------- f32 -> bf16 convert ----------------
__global__ __launch_bounds__(256) void cvt_bf16_k(const float* __restrict__ in,
                                                  __bf16* __restrict__ out, int n) {
  int i = blockIdx.x * 1024 + threadIdx.x * 4;
  if (i + 3 < n) {
    float4 v = *(const float4*)(in + i);
    union { __bf16 b[4]; unsigned long long u; } r;
    r.b[0] = (__bf16)v.x; r.b[1] = (__bf16)v.y;
    r.b[2] = (__bf16)v.z; r.b[3] = (__bf16)v.w;
    *(unsigned long long*)(out + i) = r.u;
  }
}

// ---------------- W[k][n] f32 -> WT[n][k] bf16 ----------------
__global__ __launch_bounds__(256) void wtrans_k(const float* __restrict__ W,
                                                __bf16* __restrict__ WT) {
  __shared__ float tile[64][65];
  int k0 = blockIdx.x * 64, n0 = blockIdx.y * 64;
  int t = threadIdx.x, r = t >> 4, c4 = (t & 15) * 4;
#pragma unroll
  for (int p = 0; p < 4; ++p) {
    float4 v = *(const float4*)(W + (size_t)(k0 + r + 16 * p) * 1024 + n0 + c4);
    *(float4*)&tile[r + 16 * p][c4] = v;
  }
  __syncthreads();
#pragma unroll
  for (int p = 0; p < 4; ++p) {
    int nr = r + 16 * p;
    union { __bf16 b[4]; unsigned long long u; } o;
#pragma unroll
    for (int i = 0; i < 4; ++i) o.b[i] = (__bf16)tile[c4 + i][nr];
    *(unsigned long long*)(WT + (size_t)(n0 + nr) * 1024 + k0 + c4) = o.u;
  }
}

// ------- pack masks to bitfields: mbits[tn(z)][b][j][1024 i-bits] -------
__global__ __launch_bounds__(256) void packbits_k(const float* __restrict__ mh,
                                                  const float* __restrict__ mg,
                                                  unsigned int* __restrict__ mbits) {
  __shared__ unsigned char nib[2][16][64];
  const int t = threadIdx.x;
  const int i0b = blockIdx.x * 64;
  const int jb0 = blockIdx.y * 64;
  const float* srcs[2] = {mh, mg};
#pragma unroll
  for (int tn = 0; tn < 2; ++tn) {
    const float* in = srcs[tn];
#pragma unroll
    for (int p = 0; p < 4; ++p) {
      int item = t + 256 * p;
      int iloc = item >> 4, jbq = item & 15;
      float4 v = *(const float4*)(in + (size_t)(i0b + iloc) * 4096 + jb0 + jbq * 4);
      unsigned char nb = (v.x > 0.5f ? 1 : 0) | (v.y > 0.5f ? 2 : 0) |
                         (v.z > 0.5f ? 4 : 0) | (v.w > 0.5f ? 8 : 0);
      nib[tn][jbq][iloc] = nb;
    }
  }
  __syncthreads();
  {
    int tn = t >> 7, rem = t & 127;
    int jbl = rem >> 1, dw = rem & 1;
    int jbq = jbl >> 2, e = jbl & 3;
    uint4 u0 = *(uint4*)&nib[tn][jbq][32 * dw];
    uint4 u1 = *(uint4*)&nib[tn][jbq][32 * dw + 16];
    unsigned d[8] = {u0.x, u0.y, u0.z, u0.w, u1.x, u1.y, u1.z, u1.w};
    unsigned out = 0;
#pragma unroll
    for (int c = 0; c < 8; ++c) {
      unsigned bits = (d[c] >> e) & 0x01010101u;
      unsigned nv = ((bits * 0x01020408u) >> 24) & 0xFu;
      out |= nv << (4 * c);
    }
    int jb = jb0 + jbl;
    int b = jb & 3, j = jb >> 2;
    mbits[(size_t)(((tn * 4 + b) * 1024 + j)) * 32 + (i0b >> 5) + dw] = out;
  }
}

// ------- segv[b][j] = seg-bit of token j -------
__global__ __launch_bounds__(256) void segv_k(const float* __restrict__ seg,
                                              unsigned char* __restrict__ segv) {
  int id = blockIdx.x * 256 + threadIdx.x;
  if (id < 4096) {
    int b = id >> 10, j = id & 1023;
    segv[b * 1024 + j] = (seg[(size_t)(j * 4 + b) * 2 + 1] > 0.5f) ? 1 : 0;
  }
}

// ---------------- bf16 MFMA GEMM: C[M][1024] = A[M][1024] * BT^T ----------------
template <bool OUT_BF16>
__global__ __launch_bounds__(256) void gemm_mfma(const __bf16* __restrict__ A,
                                                 const __bf16* __restrict__ BT,
                                                 void* __restrict__ Cout) {
  alignas(16) __shared__ __bf16 sA[128 * 64];
  alignas(16) __shared__ __bf16 sB[128 * 64];
  const int t = threadIdx.x;
  const int lane = t & 63, wave = t >> 6;
  // XCD remap: each XCD owns a contiguous M-stripe across all N (A fetched once)
  const int lin = blockIdx.y * 8 + blockIdx.x;
  const int xcd = lin & 7, l = lin >> 3;
  const int n0 = (l & 7) * 128;
  const size_t m0 = (size_t)(xcd * (gridDim.y >> 3) + (l >> 3)) * 128;
  const int wm = (wave >> 1) * 64, wn = (wave & 1) * 64;

  f32x16 acc[2][2];
#pragma unroll
  for (int a = 0; a < 2; ++a)
#pragma unroll
    for (int b = 0; b < 2; ++b)
#pragma unroll
      for (int i = 0; i < 16; ++i) acc[a][b][i] = 0.f;

  for (int k0 = 0; k0 < 1024; k0 += 64) {
    __syncthreads();
#pragma unroll
    for (int p = 0; p < 4; ++p) {
      int idx = t + 256 * p;
      int row = idx >> 3, blk = idx & 7;
      int sblk = (blk ^ (row & 7)) * 8;
      gld16(A + (m0 + row) * 1024 + k0 + sblk, (char*)sA + idx * 16);
      gld16(BT + (size_t)(n0 + row) * 1024 + k0 + sblk, (char*)sB + idx * 16);
    }
    __syncthreads();
#pragma unroll
    for (int kk = 0; kk < 4; ++kk) {
      int blk = 2 * kk + (lane >> 5);
      bf16x8 af[2], bfr[2];
#pragma unroll
      for (int mi = 0; mi < 2; ++mi)
        af[mi] = *(bf16x8*)((char*)sA + swzb(wm + mi * 32 + (lane & 31), blk));
#pragma unroll
      for (int ni = 0; ni < 2; ++ni)
        bfr[ni] = *(bf16x8*)((char*)sB + swzb(wn + ni * 32 + (lane & 31), blk));
#pragma unroll
      for (int mi = 0; mi < 2; ++mi)
#pragma unroll
        for (int ni = 0; ni < 2; ++ni)
          acc[mi][ni] = __builtin_amdgcn_mfma_f32_32x32x16_bf16(
              af[mi], bfr[ni], acc[mi][ni], 0, 0, 0);
    }
  }
#pragma unroll
  for (int mi = 0; mi < 2; ++mi)
#pragma unroll
    for (int ni = 0; ni < 2; ++ni)
#pragma unroll
      for (int rg = 0; rg < 16; ++rg) {
        int row = wm + mi * 32 + (rg & 3) + 8 * (rg >> 2) + 4 * (lane >> 5);
        int col = wn + ni * 32 + (lane & 31);
        float v = acc[mi][ni][rg];
        if (OUT_BF16)
          ((__bf16*)Cout)[(m0 + row) * 1024 + n0 + col] = (__bf16)v;
        else
          ((float*)Cout)[(m0 + row) * 1024 + n0 + col] = v;
      }
}

// ---------------- V transpose: vhb [tok][(b,n,d)] -> vtb [(b,n,d)][tok] ----------------
__global__ __launch_bounds__(256) void vtrans_k(const __bf16* __restrict__ vhb,
                                                __bf16* __restrict__ vtb) {
  alignas(16) __shared__ __bf16 st[64 * 128];
  const int t = threadIdx.x;
  const int tok0 = blockIdx.x * 128;
  const int bn = blockIdx.y;
  const int b = bn >> 4, n = bn & 15;
#pragma unroll
  for (int p = 0; p < 4; ++p) {
    int item = t + 256 * p;
    int tok = item >> 3, c8 = item & 7;
    BV8 v;
    v.u = *(const uint4*)(vhb + ((size_t)((tok0 + tok) * 4 + b)) * 1024 + n * 64 + c8 * 8);
#pragma unroll
    for (int e = 0; e < 8; ++e) {
      int d = c8 * 8 + e;
      *(__bf16*)((char*)st + d * 256 + ((2 * tok) ^ (((d >> 3) & 7) << 4))) = v.e[e];
    }
  }
  __syncthreads();
#pragma unroll
  for (int p = 0; p < 4; ++p) {
    int item = t + 256 * p;
    int d = item >> 4, tc = (item & 15) * 8;
    uint4 v = *(uint4*)((char*)st + d * 256 + ((2 * tc) ^ (((d >> 3) & 7) << 4)));
    *(uint4*)(vtb + ((size_t)(bn * 64 + d)) * 1024 + tok0 + tc) = v;
  }
}

// ------- fused relative attention v5: in-order pipeline, 1 barrier/iter -------
__global__ __launch_bounds__(256, 3) void attn5(
    const __bf16* __restrict__ qpb, const __bf16* __restrict__ kb,
    const __bf16* __restrict__ vtb, const __bf16* __restrict__ krb,
    const unsigned int* __restrict__ mbits, const unsigned char* __restrict__ segv,
    const float* __restrict__ se, const float* __restrict__ rwb,
    const float* __restrict__ rrb, const float* __restrict__ rsb,
    __bf16* __restrict__ av) {
  const int t = threadIdx.x;
  const int lane = t & 63, wave = t >> 6;
  const int hlf = lane >> 5, ln31 = lane & 31;
  const int qh = wave >> 1, kh = wave & 1;

  // XCD-aware 1D decode: 8 heads of one batch per XCD
  const int bid = blockIdx.x;
  const int xcd = bid & 7, idx0 = bid >> 3;
  const int bn = xcd * 8 + (idx0 & 7);
  const int i0 = ((idx0 >> 3) & 15) * 64;
  const int z = idx0 >> 7;
  const int b = bn >> 4, n = bn & 15;

  alignas(16) __shared__ __bf16 ring[8 * 32 * 64];   // 32KB Kr sliding window
  alignas(16) __shared__ __bf16 sp[2][2][32 * 64];   // 16KB P double-buffered
  __shared__ float sl[4][2][16];

  const int wpro = 960 - i0;  // ring prologue base (>=0, mult of 32)
  // ---- prologue: stage ring rows [wpro, wpro+127] ----
#pragma unroll
  for (int p = 0; p < 4; ++p) {
    int item = t + 256 * p;
    int wl = item >> 3, blk = item & 7;
    int w = wpro + wl;
    int wc = min(w, 2047);
    gld16(krb + ((size_t)(wc * 4 + b)) * 1024 + n * 64 + ((blk ^ (w & 7)) << 3),
          (char*)ring + ((w >> 5) & 7) * 4096 + (w & 31) * 128 + blk * 16);
  }
  __builtin_amdgcn_sched_barrier(0);

  // ---- Q fragments (+biases), alpha/beta for segment fold ----
  const size_t qbase =
      ((size_t)((z * 1024 + i0 + 32 * qh + ln31) * 4 + b)) * 1024 + n * 64;
  bf16x8 qw[4], qr[4];
  float e0 = 0.f, e1 = 0.f;
#pragma unroll
  for (int kk = 0; kk < 4; ++kk) {
    BV8 raw;
    raw.u = *(const uint4*)(qpb + qbase + 16 * kk + 8 * hlf);
    int d0 = 16 * kk + 8 * hlf;
    float4 w0 = *(const float4*)(rwb + n * 64 + d0);
    float4 w1 = *(const float4*)(rwb + n * 64 + d0 + 4);
    float4 r0 = *(const float4*)(rrb + n * 64 + d0);
    float4 r1 = *(const float4*)(rrb + n * 64 + d0 + 4);
    float4 sb0 = *(const float4*)(rsb + n * 64 + d0);
    float4 sb1 = *(const float4*)(rsb + n * 64 + d0 + 4);
    float4 ea0 = *(const float4*)(se + n * 64 + d0);
    float4 ea1 = *(const float4*)(se + n * 64 + d0 + 4);
    float4 eb0 = *(const float4*)(se + 1024 + n * 64 + d0);
    float4 eb1 = *(const float4*)(se + 1024 + n * 64 + d0 + 4);
    float wv[8] = {w0.x, w0.y, w0.z, w0.w, w1.x, w1.y, w1.z, w1.w};
    float rv[8] = {r0.x, r0.y, r0.z, r0.w, r1.x, r1.y, r1.z, r1.w};
    float sv_[8] = {sb0.x, sb0.y, sb0.z, sb0.w, sb1.x, sb1.y, sb1.z, sb1.w};
    float ev0[8] = {ea0.x, ea0.y, ea0.z, ea0.w, ea1.x, ea1.y, ea1.z, ea1.w};
    float ev1[8] = {eb0.x, eb0.y, eb0.z, eb0.w, eb1.x, eb1.y, eb1.z, eb1.w};
    BV8 qwv, qrv;
#pragma unroll
    for (int i = 0; i < 8; ++i) {
      float f = (float)raw.e[i];
      qwv.e[i] = (__bf16)(f + wv[i]);
      qrv.e[i] = (__bf16)(f + rv[i]);
      float fs = f + sv_[i];
      e0 += fs * ev0[i];
      e1 += fs * ev1[i];
    }
    qw[kk] = qwv.v;
    qr[kk] = qrv.v;
  }
  e0 += __shfl_xor(e0, 32);
  e1 += __shfl_xor(e1, 32);
  float si = (float)segv[b * 1024 + i0 + 32 * qh + ln31];
  float alpha = e0 + (e1 - e0) * si;
  float beta = (e1 - e0) * (1.f - 2.f * si);
  bf16x8 augA;
  {
    BV8 aa;
    aa.w[0] = aa.w[1] = aa.w[2] = aa.w[3] = 0;
    if (!hlf) {
      union { __bf16 b2[2]; unsigned u; } w2;
      w2.b2[0] = (__bf16)alpha;
      w2.b2[1] = (__bf16)beta;
      aa.w[0] = w2.u;
    }
    augA = aa.v;
  }

  f32x16 oacc, colsum;
#pragma unroll
  for (int i = 0; i < 16; ++i) { oacc[i] = 0.f; colsum[i] = 0.f; }

  const unsigned char* segp = segv + b * 1024;
  const __bf16* kbase = kb + ((size_t)((32 * kh + ln31) * 4 + b)) * 1024 + n * 64 + 8 * hlf;
  const __bf16* vbase = vtb + ((size_t)(bn * 64 + 32 * kh + ln31)) * 1024 + 8 * hlf;
  const size_t mbase = (size_t)((z * 4 + b) * 1024 + 32 * kh + ln31) * 32 + (i0 >> 5) + qh;

  __syncthreads();  // prologue ring visible (full drain, once)

  for (int jt = 0; jt < 16; ++jt) {
    const int J0 = 64 * jt;
    // ---- (A) stage next 2 ring slots: the OLDEST in-flight VMEM ----
    if (jt < 15) {
      int wsb = wpro + 128 + 64 * jt;
#pragma unroll
      for (int p = 0; p < 2; ++p) {
        int item = t + 256 * p;
        int wl = item >> 3, blk = item & 7;
        int w = wsb + wl;
        int wc = min(w, 2047);
        gld16(krb + ((size_t)(wc * 4 + b)) * 1024 + n * 64 + ((blk ^ (w & 7)) << 3),
              (char*)ring + ((w >> 5) & 7) * 4096 + (w & 31) * 128 + blk * 16);
      }
    }
    __builtin_amdgcn_sched_barrier(0);

    // ---- (B) this-iter loads: kf, mask, seg (in-flight under BD) ----
    bf16x8 kf[4];
#pragma unroll
    for (int kk = 0; kk < 4; ++kk)
      kf[kk] = *(const bf16x8*)(kbase + (size_t)J0 * 4096 + 16 * kk);
    unsigned praw = mbits[mbase + (size_t)J0 * 32];
    unsigned sj = segp[J0 + 32 * kh + ln31];
    bf16x8 augB;
    {
      BV8 bb2;
      bb2.w[0] = hlf ? 0u : (0x3F80u | (sj * 0x3F800000u));
      bb2.w[1] = bb2.w[2] = bb2.w[3] = 0;
      augB = bb2.v;
    }

    // ---- (C) BD (ring, LDS) then AC (kf auto-wait retires ring too) ----
    const int base0 = J0 + 32 * (kh - qh) + 993 - i0;
    f32x16 bd[2];
    f32x16 ac;
#pragma unroll
    for (int i = 0; i < 16; ++i) { bd[0][i] = 0.f; bd[1][i] = 0.f; ac[i] = 0.f; }
    __builtin_amdgcn_s_setprio(1);
#pragma unroll
    for (int tt = 0; tt < 2; ++tt) {
      int w = base0 + 32 * tt + ln31;
      int rbyte = ((w >> 5) & 7) * 4096 + (w & 31) * 128;
      int wx = (w & 7) << 4;
#pragma unroll
      for (int kk = 0; kk < 4; ++kk) {
        bf16x8 bbr = *(const bf16x8*)((char*)ring + rbyte + (((2 * kk + hlf) << 4) ^ wx));
        bd[tt] = __builtin_amdgcn_mfma_f32_32x32x16_bf16(qr[kk], bbr, bd[tt], 0, 0, 0);
      }
    }
#pragma unroll
    for (int kk = 0; kk < 4; ++kk)
      ac = __builtin_amdgcn_mfma_f32_32x32x16_bf16(qw[kk], kf[kk], ac, 0, 0, 0);
    ac = __builtin_amdgcn_mfma_f32_32x32x16_bf16(augA, augB, ac, 0, 0, 0);
    __builtin_amdgcn_s_setprio(0);

    // ---- (D) V frags: issued now, consumed after the barrier ----
    bf16x8 vf[4];
#pragma unroll
    for (int kk = 0; kk < 4; ++kk)
      vf[kk] = *(const bf16x8*)(vbase + J0 + 16 * kk);

    // ---- (E) realign BD + score + P write (buffer jt&1) ----
    char* spw = (char*)&sp[jt & 1][qh][0];
#pragma unroll
    for (int rg = 0; rg < 16; ++rg) {
      int q_ = (rg & 3) + 8 * (rg >> 2) + 4 * hlf;
      int jsrc = (ln31 + q_ + 1) & 31;
      float selv = (jsrc > q_) ? bd[1][rg] : bd[0][rg];
      int addr = ((lane & 32) | ((ln31 + 31 - q_) & 31)) << 2;
      float bdr = __int_as_float(
          __builtin_amdgcn_ds_bpermute(addr, __float_as_int(selv)));
      float s = (ac[rg] + bdr) * 0.18033688f;  // 0.125*log2(e)
      float p = __builtin_amdgcn_exp2f(s);
      int sh = (rg & 3) + 8 * (rg >> 2);
      p = ((praw >> (hlf * 4 + sh)) & 1) ? 0.f : p;
      colsum[rg] += p;
      *(__bf16*)(spw + q_ * 128 + ((2 * (32 * kh + ln31)) ^ ((q_ & 7) << 4))) =
          (__bf16)p;
    }

    // ---- (F) single counted barrier: only vf may stay in flight ----
    asm volatile("s_waitcnt vmcnt(4) lgkmcnt(0)\n\ts_barrier" ::: "memory");
    __builtin_amdgcn_sched_barrier(0);

    // ---- (G) PV ----
    __builtin_amdgcn_s_setprio(1);
#pragma unroll
    for (int kk = 0; kk < 4; ++kk) {
      bf16x8 pa = *(const bf16x8*)(
          spw + ln31 * 128 + ((32 * kk + 16 * hlf) ^ ((ln31 & 7) << 4)));
      oacc = __builtin_amdgcn_mfma_f32_32x32x16_bf16(pa, vf[kk], oacc, 0, 0, 0);
    }
    __builtin_amdgcn_s_setprio(0);
  }

  // ---- epilogue: l reduce + merge + scale + store ----
#pragma unroll
  for (int m = 1; m <= 16; m <<= 1)
#pragma unroll
    for (int rg = 0; rg < 16; ++rg) colsum[rg] += __shfl_xor(colsum[rg], m);
  __syncthreads();
  if (ln31 == 0) {
#pragma unroll
    for (int rg = 0; rg < 16; ++rg) sl[wave][hlf][rg] = colsum[rg];
  }
  __syncthreads();
#pragma unroll
  for (int rg = 0; rg < 16; ++rg) {
    float l = sl[2 * qh][hlf][rg] + sl[2 * qh + 1][hlf][rg];
    float rl = __fdividef(1.f, l);
    int qrow = 32 * qh + (rg & 3) + 8 * (rg >> 2) + 4 * hlf;
    av[((size_t)((z * 1024 + i0 + qrow) * 4 + b)) * 1024 + n * 64 + 32 * kh + ln31] =
        (__bf16)(oacc[rg] * rl);
  }
}

// ------------- residual add + LayerNorm (in-place on io) -------------
__global__ __launch_bounds__(256) void add_ln(float* __restrict__ io,
                                              const float* __restrict__ h,
                                              const float* __restrict__ g,
                                              const float* __restrict__ gam,
                                              const float* __restrict__ bet) {
  const size_t row = blockIdx.x;
  float* o = io + row * 1024;
  const float* x = (row < 4096) ? (h + row * 1024) : (g + (row - 4096) * 1024);
  const int t = threadIdx.x;
  float v[4];
  float s1 = 0.f, s2 = 0.f;
#pragma unroll
  for (int k = 0; k < 4; ++k) {
    int idx = t + 256 * k;
    v[k] = o[idx] + x[idx];
    s1 += v[k];
    s2 += v[k] * v[k];
  }
#pragma unroll
  for (int off = 32; off >= 1; off >>= 1) {
    s1 += __shfl_xor(s1, off);
    s2 += __shfl_xor(s2, off);
  }
  __shared__ float r1[4], r2[4];
  if ((t & 63) == 0) { r1[t >> 6] = s1; r2[t >> 6] = s2; }
  __syncthreads();
  s1 = r1[0] + r1[1] + r1[2] + r1[3];
  s2 = r2[0] + r2[1] + r2[2] + r2[3];
  float mean = s1 * (1.f / 1024.f);
  float var = s2 * (1.f / 1024.f) - mean * mean;
  float rstd = rsqrtf(fmaxf(var, 0.f) + 1e-12f);
#pragma unroll
  for (int k = 0; k < 4; ++k) {
    int idx = t + 256 * k;
    o[idx] = (v[k] - mean) * rstd * gam[idx] + bet[idx];
  }
}

extern "C" void kernel_launch(void* const* d_in, const int* in_sizes, int n_in,
                              void* d_out, int out_size, void* d_ws,
                              size_t ws_size, hipStream_t stream) {
  const float* h = (const float*)d_in[0];
  const float* g = (const float*)d_in[1];
  const float* mh = (const float*)d_in[2];
  const float* mg = (const float*)d_in[3];
  const float* r = (const float*)d_in[4];
  const float* seg = (const float*)d_in[5];
  const float* q_w = (const float*)d_in[6];
  const float* k_w = (const float*)d_in[7];
  const float* v_w = (const float*)d_in[8];
  const float* o_w = (const float*)d_in[9];
  const float* r_w = (const float*)d_in[10];
  const float* rrb = (const float*)d_in[11];
  const float* rsb = (const float*)d_in[12];
  const float* rwb = (const float*)d_in[13];
  const float* se = (const float*)d_in[14];
  const float* gam = (const float*)d_in[15];
  const float* bet = (const float*)d_in[16];
  float* out = (float*)d_out;

  // ---- ws layout ----
  char* w = (char*)d_ws;
  __bf16* hgb = (__bf16*)w;                 // 16MB [8192][1024]
  __bf16* vtb = (__bf16*)w;                 // aliases hgb (dead after q-GEMM)
  w += (size_t)16 << 20;
  __bf16* rb = (__bf16*)w;                  // 16MB
  __bf16* avb = (__bf16*)w;                 // aliases rb (dead after r-GEMM)
  w += (size_t)16 << 20;
  __bf16* qwt = (__bf16*)w; w += (size_t)2 << 20;
  __bf16* kwt = (__bf16*)w; w += (size_t)2 << 20;
  __bf16* vwt = (__bf16*)w; w += (size_t)2 << 20;
  __bf16* rwt = (__bf16*)w; w += (size_t)2 << 20;
  __bf16* owt = (__bf16*)w; w += (size_t)2 << 20;
  __bf16* qpb = (__bf16*)w; w += (size_t)16 << 20;  // [8192][1024]
  __bf16* khb = (__bf16*)w; w += (size_t)8 << 20;
  __bf16* vhb = (__bf16*)w; w += (size_t)8 << 20;
  __bf16* krb = (__bf16*)w; w += (size_t)16 << 20;
  unsigned int* mbits = (unsigned int*)w; w += (size_t)1 << 20;
  unsigned char* segvb = (unsigned char*)w; w += 4096;

  dim3 blk(256);

  cvt_bf16_k<<<4096, blk, 0, stream>>>(h, hgb, 4194304);
  cvt_bf16_k<<<4096, blk, 0, stream>>>(g, hgb + 4194304, 4194304);
  cvt_bf16_k<<<8192, blk, 0, stream>>>(r, rb, 8388608);
  cvt_bf16_k<<<1024, blk, 0, stream>>>(o_w, owt, 1048576);
  wtrans_k<<<dim3(16, 16), blk, 0, stream>>>(q_w, qwt);
  wtrans_k<<<dim3(16, 16), blk, 0, stream>>>(k_w, kwt);
  wtrans_k<<<dim3(16, 16), blk, 0, stream>>>(v_w, vwt);
  wtrans_k<<<dim3(16, 16), blk, 0, stream>>>(r_w, rwt);
  packbits_k<<<dim3(16, 64), blk, 0, stream>>>(mh, mg, mbits);
  segv_k<<<16, blk, 0, stream>>>(seg, segvb);

  gemm_mfma<true><<<dim3(8, 32), blk, 0, stream>>>(hgb, kwt, khb);
  gemm_mfma<true><<<dim3(8, 32), blk, 0, stream>>>(hgb, vwt, vhb);
  gemm_mfma<true><<<dim3(8, 64), blk, 0, stream>>>(rb, rwt, krb);
  gemm_mfma<true><<<dim3(8, 64), blk, 0, stream>>>(hgb, qwt, qpb);  // hgb dead after
  vtrans_k<<<dim3(8, 64), blk, 0, stream>>>(vhb, vtb);

  attn5<<<2048, blk, 0, stream>>>(qpb, khb, vtb, krb, mbits, segvb, se, rwb,
                                  rrb, rsb, avb);

  gemm_mfma<false><<<dim3(8, 64), blk, 0, stream>>>(avb, owt, out);
  add_ln<<<8192, blk, 0, stream>>>(out, h, g, gam, bet);
}

// Round 10
// 690.375 us; speedup vs baseline: 1.5843x; 1.2196x over previous
//
#include <hip/hip_runtime.h>
#include <math.h>

#define QS 1024
#define BSZ 4
#define NH 16
#define RL 2048

typedef __attribute__((ext_vector_type(8))) __bf16 bf16x8;
typedef __attribute__((ext_vector_type(16))) float f32x16;
typedef __attribute__((ext_vector_type(4))) float f32x4;

union BV8 { bf16x8 v; uint4 u; __bf16 e[8]; unsigned w[4]; };

// byte offset in a [rows][64 bf16] tile, 128B rows, blk-XOR swizzle
__device__ __forceinline__ int swzb(int row, int blk) {
  return row * 128 + (((blk ^ row) & 7) << 4);
}

typedef __attribute__((address_space(3))) unsigned int lds_u32;
typedef __attribute__((address_space(1))) const unsigned int glb_u32;
__device__ __forceinline__ void gld16(const void* g, void* l) {
  __builtin_amdgcn_global_load_lds((glb_u32*)g, (lds_u32*)l, 16, 0, 0);
}

// ---------------- f32 -> bf16 convert ----------------
__global__ __launch_bounds__(256) void cvt_bf16_k(const float* __restrict__ in,
                                                  __bf16* __restrict__ out, int n) {
  int i = blockIdx.x * 1024 + threadIdx.x * 4;
  if (i + 3 < n) {
    float4 v = *(const float4*)(in + i);
    union { __bf16 b[4]; unsigned long long u; } r;
    r.b[0] = (__bf16)v.x; r.b[1] = (__bf16)v.y;
    r.b[2] = (__bf16)v.z; r.b[3] = (__bf16)v.w;
    *(unsigned long long*)(out + i) = r.u;
  }
}

// ---------------- W[k][n] f32 -> WT[n][k] bf16 ----------------
__global__ __launch_bounds__(256) void wtrans_k(const float* __restrict__ W,
                                                __bf16* __restrict__ WT) {
  __shared__ float tile[64][65];
  int k0 = blockIdx.x * 64, n0 = blockIdx.y * 64;
  int t = threadIdx.x, r = t >> 4, c4 = (t & 15) * 4;
#pragma unroll
  for (int p = 0; p < 4; ++p) {
    float4 v = *(const float4*)(W + (size_t)(k0 + r + 16 * p) * 1024 + n0 + c4);
    *(float4*)&tile[r + 16 * p][c4] = v;
  }
  __syncthreads();
#pragma unroll
  for (int p = 0; p < 4; ++p) {
    int nr = r + 16 * p;
    union { __bf16 b[4]; unsigned long long u; } o;
#pragma unroll
    for (int i = 0; i < 4; ++i) o.b[i] = (__bf16)tile[c4 + i][nr];
    *(unsigned long long*)(WT + (size_t)(n0 + nr) * 1024 + k0 + c4) = o.u;
  }
}

// ------- pack masks to bitfields: mbits[tn(z)][b][j][1024 i-bits] -------
__global__ __launch_bounds__(256) void packbits_k(const float* __restrict__ mh,
                                                  const float* __restrict__ mg,
                                                  unsigned int* __restrict__ mbits) {
  __shared__ unsigned char nib[2][16][64];
  const int t = threadIdx.x;
  const int i0b = blockIdx.x * 64;
  const int jb0 = blockIdx.y * 64;
  const float* srcs[2] = {mh, mg};
#pragma unroll
  for (int tn = 0; tn < 2; ++tn) {
    const float* in = srcs[tn];
#pragma unroll
    for (int p = 0; p < 4; ++p) {
      int item = t + 256 * p;
      int iloc = item >> 4, jbq = item & 15;
      float4 v = *(const float4*)(in + (size_t)(i0b + iloc) * 4096 + jb0 + jbq * 4);
      unsigned char nb = (v.x > 0.5f ? 1 : 0) | (v.y > 0.5f ? 2 : 0) |
                         (v.z > 0.5f ? 4 : 0) | (v.w > 0.5f ? 8 : 0);
      nib[tn][jbq][iloc] = nb;
    }
  }
  __syncthreads();
  {
    int tn = t >> 7, rem = t & 127;
    int jbl = rem >> 1, dw = rem & 1;
    int jbq = jbl >> 2, e = jbl & 3;
    uint4 u0 = *(uint4*)&nib[tn][jbq][32 * dw];
    uint4 u1 = *(uint4*)&nib[tn][jbq][32 * dw + 16];
    unsigned d[8] = {u0.x, u0.y, u0.z, u0.w, u1.x, u1.y, u1.z, u1.w};
    unsigned out = 0;
#pragma unroll
    for (int c = 0; c < 8; ++c) {
      unsigned bits = (d[c] >> e) & 0x01010101u;
      unsigned nv = ((bits * 0x01020408u) >> 24) & 0xFu;
      out |= nv << (4 * c);
    }
    int jb = jb0 + jbl;
    int b = jb & 3, j = jb >> 2;
    mbits[(size_t)(((tn * 4 + b) * 1024 + j)) * 32 + (i0b >> 5) + dw] = out;
  }
}

// ------- segv[b][j] = seg-bit of token j -------
__global__ __launch_bounds__(256) void segv_k(const float* __restrict__ seg,
                                              unsigned char* __restrict__ segv) {
  int id = blockIdx.x * 256 + threadIdx.x;
  if (id < 4096) {
    int b = id >> 10, j = id & 1023;
    segv[b * 1024 + j] = (seg[(size_t)(j * 4 + b) * 2 + 1] > 0.5f) ? 1 : 0;
  }
}

// ---------------- bf16 MFMA GEMM: C[M][1024] = A[M][1024] * BT^T ----------------
template <bool OUT_BF16>
__global__ __launch_bounds__(256) void gemm_mfma(const __bf16* __restrict__ A,
                                                 const __bf16* __restrict__ BT,
                                                 void* __restrict__ Cout) {
  alignas(16) __shared__ __bf16 sA[128 * 64];
  alignas(16) __shared__ __bf16 sB[128 * 64];
  const int t = threadIdx.x;
  const int lane = t & 63, wave = t >> 6;
  // XCD remap: each XCD owns a contiguous M-stripe across all N (A fetched once)
  const int lin = blockIdx.y * 8 + blockIdx.x;
  const int xcd = lin & 7, l = lin >> 3;
  const int n0 = (l & 7) * 128;
  const size_t m0 = (size_t)(xcd * (gridDim.y >> 3) + (l >> 3)) * 128;
  const int wm = (wave >> 1) * 64, wn = (wave & 1) * 64;

  f32x16 acc[2][2];
#pragma unroll
  for (int a = 0; a < 2; ++a)
#pragma unroll
    for (int b = 0; b < 2; ++b)
#pragma unroll
      for (int i = 0; i < 16; ++i) acc[a][b][i] = 0.f;

  for (int k0 = 0; k0 < 1024; k0 += 64) {
    __syncthreads();
#pragma unroll
    for (int p = 0; p < 4; ++p) {
      int idx = t + 256 * p;
      int row = idx >> 3, blk = idx & 7;
      int sblk = (blk ^ (row & 7)) * 8;
      gld16(A + (m0 + row) * 1024 + k0 + sblk, (char*)sA + idx * 16);
      gld16(BT + (size_t)(n0 + row) * 1024 + k0 + sblk, (char*)sB + idx * 16);
    }
    __syncthreads();
#pragma unroll
    for (int kk = 0; kk < 4; ++kk) {
      int blk = 2 * kk + (lane >> 5);
      bf16x8 af[2], bfr[2];
#pragma unroll
      for (int mi = 0; mi < 2; ++mi)
        af[mi] = *(bf16x8*)((char*)sA + swzb(wm + mi * 32 + (lane & 31), blk));
#pragma unroll
      for (int ni = 0; ni < 2; ++ni)
        bfr[ni] = *(bf16x8*)((char*)sB + swzb(wn + ni * 32 + (lane & 31), blk));
#pragma unroll
      for (int mi = 0; mi < 2; ++mi)
#pragma unroll
        for (int ni = 0; ni < 2; ++ni)
          acc[mi][ni] = __builtin_amdgcn_mfma_f32_32x32x16_bf16(
              af[mi], bfr[ni], acc[mi][ni], 0, 0, 0);
    }
  }
#pragma unroll
  for (int mi = 0; mi < 2; ++mi)
#pragma unroll
    for (int ni = 0; ni < 2; ++ni)
#pragma unroll
      for (int rg = 0; rg < 16; ++rg) {
        int row = wm + mi * 32 + (rg & 3) + 8 * (rg >> 2) + 4 * (lane >> 5);
        int col = wn + ni * 32 + (lane & 31);
        float v = acc[mi][ni][rg];
        if (OUT_BF16)
          ((__bf16*)Cout)[(m0 + row) * 1024 + n0 + col] = (__bf16)v;
        else
          ((float*)Cout)[(m0 + row) * 1024 + n0 + col] = v;
      }
}

// ---------------- V transpose: vhb [tok][(b,n,d)] -> vtb [(b,n,d)][tok] ----------------
__global__ __launch_bounds__(256) void vtrans_k(const __bf16* __restrict__ vhb,
                                                __bf16* __restrict__ vtb) {
  alignas(16) __shared__ __bf16 st[64 * 128];
  const int t = threadIdx.x;
  const int tok0 = blockIdx.x * 128;
  const int bn = blockIdx.y;
  const int b = bn >> 4, n = bn & 15;
#pragma unroll
  for (int p = 0; p < 4; ++p) {
    int item = t + 256 * p;
    int tok = item >> 3, c8 = item & 7;
    BV8 v;
    v.u = *(const uint4*)(vhb + ((size_t)((tok0 + tok) * 4 + b)) * 1024 + n * 64 + c8 * 8);
#pragma unroll
    for (int e = 0; e < 8; ++e) {
      int d = c8 * 8 + e;
      *(__bf16*)((char*)st + d * 256 + ((2 * tok) ^ (((d >> 3) & 7) << 4))) = v.e[e];
    }
  }
  __syncthreads();
#pragma unroll
  for (int p = 0; p < 4; ++p) {
    int item = t + 256 * p;
    int d = item >> 4, tc = (item & 15) * 8;
    uint4 v = *(uint4*)((char*)st + d * 256 + ((2 * tc) ^ (((d >> 3) & 7) << 4)));
    *(uint4*)(vtb + ((size_t)(bn * 64 + d)) * 1024 + tok0 + tc) = v;
  }
}

// ------- fused relative attention v6: no ring, P-only LDS, lgkm-only barrier -------
__global__ __launch_bounds__(256, 3) void attn6(
    const __bf16* __restrict__ qpb, const __bf16* __restrict__ kb,
    const __bf16* __restrict__ vtb, const __bf16* __restrict__ krb,
    const unsigned int* __restrict__ mbits, const unsigned char* __restrict__ segv,
    const float* __restrict__ se, const float* __restrict__ rwb,
    const float* __restrict__ rrb, const float* __restrict__ rsb,
    __bf16* __restrict__ av) {
  const int t = threadIdx.x;
  const int lane = t & 63, wave = t >> 6;
  const int hlf = lane >> 5, ln31 = lane & 31;
  const int qh = wave >> 1, kh = wave & 1;

  // XCD-aware 1D decode: 8 heads of one batch per XCD
  const int bid = blockIdx.x;
  const int xcd = bid & 7, idx0 = bid >> 3;
  const int bn = xcd * 8 + (idx0 & 7);
  const int i0 = ((idx0 >> 3) & 15) * 64;
  const int z = idx0 >> 7;
  const int b = bn >> 4, n = bn & 15;

  alignas(16) __shared__ __bf16 sp[2][2][32 * 64];  // 16KB P double-buffered
  __shared__ float sl[4][2][16];

  // ---- Q fragments (+biases), alpha/beta for segment fold ----
  const size_t qbase =
      ((size_t)((z * 1024 + i0 + 32 * qh + ln31) * 4 + b)) * 1024 + n * 64;
  bf16x8 qw[4], qr[4];
  float e0 = 0.f, e1 = 0.f;
#pragma unroll
  for (int kk = 0; kk < 4; ++kk) {
    BV8 raw;
    raw.u = *(const uint4*)(qpb + qbase + 16 * kk + 8 * hlf);
    int d0 = 16 * kk + 8 * hlf;
    float4 w0 = *(const float4*)(rwb + n * 64 + d0);
    float4 w1 = *(const float4*)(rwb + n * 64 + d0 + 4);
    float4 r0 = *(const float4*)(rrb + n * 64 + d0);
    float4 r1 = *(const float4*)(rrb + n * 64 + d0 + 4);
    float4 sb0 = *(const float4*)(rsb + n * 64 + d0);
    float4 sb1 = *(const float4*)(rsb + n * 64 + d0 + 4);
    float4 ea0 = *(const float4*)(se + n * 64 + d0);
    float4 ea1 = *(const float4*)(se + n * 64 + d0 + 4);
    float4 eb0 = *(const float4*)(se + 1024 + n * 64 + d0);
    float4 eb1 = *(const float4*)(se + 1024 + n * 64 + d0 + 4);
    float wv[8] = {w0.x, w0.y, w0.z, w0.w, w1.x, w1.y, w1.z, w1.w};
    float rv[8] = {r0.x, r0.y, r0.z, r0.w, r1.x, r1.y, r1.z, r1.w};
    float sv_[8] = {sb0.x, sb0.y, sb0.z, sb0.w, sb1.x, sb1.y, sb1.z, sb1.w};
    float ev0[8] = {ea0.x, ea0.y, ea0.z, ea0.w, ea1.x, ea1.y, ea1.z, ea1.w};
    float ev1[8] = {eb0.x, eb0.y, eb0.z, eb0.w, eb1.x, eb1.y, eb1.z, eb1.w};
    BV8 qwv, qrv;
#pragma unroll
    for (int i = 0; i < 8; ++i) {
      float f = (float)raw.e[i];
      qwv.e[i] = (__bf16)(f + wv[i]);
      qrv.e[i] = (__bf16)(f + rv[i]);
      float fs = f + sv_[i];
      e0 += fs * ev0[i];
      e1 += fs * ev1[i];
    }
    qw[kk] = qwv.v;
    qr[kk] = qrv.v;
  }
  e0 += __shfl_xor(e0, 32);
  e1 += __shfl_xor(e1, 32);
  float si = (float)segv[b * 1024 + i0 + 32 * qh + ln31];
  float alpha = e0 + (e1 - e0) * si;
  float beta = (e1 - e0) * (1.f - 2.f * si);
  bf16x8 augA;
  {
    BV8 aa;
    aa.w[0] = aa.w[1] = aa.w[2] = aa.w[3] = 0;
    if (!hlf) {
      union { __bf16 b2[2]; unsigned u; } w2;
      w2.b2[0] = (__bf16)alpha;
      w2.b2[1] = (__bf16)beta;
      aa.w[0] = w2.u;
    }
    augA = aa.v;
  }

  f32x16 oacc, colsum;
#pragma unroll
  for (int i = 0; i < 16; ++i) { oacc[i] = 0.f; colsum[i] = 0.f; }

  const unsigned char* segp = segv + b * 1024;
  const __bf16* kbase =
      kb + ((size_t)((32 * kh + ln31) * 4 + b)) * 1024 + n * 64 + 8 * hlf;
  const __bf16* vbase =
      vtb + ((size_t)(bn * 64 + 32 * kh + ln31)) * 1024 + 8 * hlf;
  const __bf16* krbB = krb + (size_t)b * 1024 + n * 64 + 8 * hlf;
  const size_t mbase =
      (size_t)((z * 4 + b) * 1024 + 32 * kh + ln31) * 32 + (i0 >> 5) + qh;
  // BD window base row for this wave (tile tt adds 32*tt)
  const int wrow0 = 32 * (kh - qh) + 993 - i0 + ln31;

  for (int jt = 0; jt < 16; ++jt) {
    const int J0 = 64 * jt;
    // ---- (A) mask + seg + augB ----
    unsigned praw = mbits[mbase + (size_t)J0 * 32];
    unsigned sj = segp[J0 + 32 * kh + ln31];
    bf16x8 augB;
    {
      BV8 bb2;
      bb2.w[0] = hlf ? 0u : (0x3F80u | (sj * 0x3F800000u));
      bb2.w[1] = bb2.w[2] = bb2.w[3] = 0;
      augB = bb2.v;
    }

    // ---- (B) AC: kf transient ----
    f32x16 ac;
#pragma unroll
    for (int i = 0; i < 16; ++i) ac[i] = 0.f;
    {
      bf16x8 kf[4];
#pragma unroll
      for (int kk = 0; kk < 4; ++kk)
        kf[kk] = *(const bf16x8*)(kbase + (size_t)J0 * 4096 + 16 * kk);
      __builtin_amdgcn_s_setprio(1);
#pragma unroll
      for (int kk = 0; kk < 4; ++kk)
        ac = __builtin_amdgcn_mfma_f32_32x32x16_bf16(qw[kk], kf[kk], ac, 0, 0, 0);
      ac = __builtin_amdgcn_mfma_f32_32x32x16_bf16(augA, augB, ac, 0, 0, 0);
      __builtin_amdgcn_s_setprio(0);
    }

    // ---- (C) BD: direct global Kr, per-tile transient fragments ----
    f32x16 bd[2];
#pragma unroll
    for (int tt = 0; tt < 2; ++tt) {
#pragma unroll
      for (int i = 0; i < 16; ++i) bd[tt][i] = 0.f;
      int w = min(J0 + wrow0 + 32 * tt, 2047);
      const __bf16* krp = krbB + (size_t)w * 4096;
      bf16x8 krf[4];
#pragma unroll
      for (int kk = 0; kk < 4; ++kk)
        krf[kk] = *(const bf16x8*)(krp + 16 * kk);
      __builtin_amdgcn_s_setprio(1);
#pragma unroll
      for (int kk = 0; kk < 4; ++kk)
        bd[tt] = __builtin_amdgcn_mfma_f32_32x32x16_bf16(qr[kk], krf[kk], bd[tt], 0, 0, 0);
      __builtin_amdgcn_s_setprio(0);
    }

    // ---- (D) V frags: issued now, consumed after the barrier ----
    bf16x8 vf[4];
#pragma unroll
    for (int kk = 0; kk < 4; ++kk)
      vf[kk] = *(const bf16x8*)(vbase + J0 + 16 * kk);

    // ---- (E) realign BD + score + P write (buffer jt&1) ----
    char* spw = (char*)&sp[jt & 1][qh][0];
#pragma unroll
    for (int rg = 0; rg < 16; ++rg) {
      int q_ = (rg & 3) + 8 * (rg >> 2) + 4 * hlf;
      int jsrc = (ln31 + q_ + 1) & 31;
      float selv = (jsrc > q_) ? bd[1][rg] : bd[0][rg];
      int addr = ((lane & 32) | ((ln31 + 31 - q_) & 31)) << 2;
      float bdr = __int_as_float(
          __builtin_amdgcn_ds_bpermute(addr, __float_as_int(selv)));
      float s = (ac[rg] + bdr) * 0.18033688f;  // 0.125*log2(e)
      float p = __builtin_amdgcn_exp2f(s);
      int sh = (rg & 3) + 8 * (rg >> 2);
      p = ((praw >> (hlf * 4 + sh)) & 1) ? 0.f : p;
      colsum[rg] += p;
      *(__bf16*)(spw + q_ * 128 + ((2 * (32 * kh + ln31)) ^ ((q_ & 7) << 4))) =
          (__bf16)p;
    }

    // ---- (F) barrier: LDS-only wait; vf rides across in flight ----
    asm volatile("s_waitcnt lgkmcnt(0)\n\ts_barrier" ::: "memory");
    __builtin_amdgcn_sched_barrier(0);

    // ---- (G) PV ----
    __builtin_amdgcn_s_setprio(1);
#pragma unroll
    for (int kk = 0; kk < 4; ++kk) {
      bf16x8 pa = *(const bf16x8*)(
          spw + ln31 * 128 + ((32 * kk + 16 * hlf) ^ ((ln31 & 7) << 4)));
      oacc = __builtin_amdgcn_mfma_f32_32x32x16_bf16(pa, vf[kk], oacc, 0, 0, 0);
    }
    __builtin_amdgcn_s_setprio(0);
  }

  // ---- epilogue: l reduce + merge + scale + store ----
#pragma unroll
  for (int m = 1; m <= 16; m <<= 1)
#pragma unroll
    for (int rg = 0; rg < 16; ++rg) colsum[rg] += __shfl_xor(colsum[rg], m);
  __syncthreads();
  if (ln31 == 0) {
#pragma unroll
    for (int rg = 0; rg < 16; ++rg) sl[wave][hlf][rg] = colsum[rg];
  }
  __syncthreads();
#pragma unroll
  for (int rg = 0; rg < 16; ++rg) {
    float l = sl[2 * qh][hlf][rg] + sl[2 * qh + 1][hlf][rg];
    float rl = __fdividef(1.f, l);
    int qrow = 32 * qh + (rg & 3) + 8 * (rg >> 2) + 4 * hlf;
    av[((size_t)((z * 1024 + i0 + qrow) * 4 + b)) * 1024 + n * 64 + 32 * kh + ln31] =
        (__bf16)(oacc[rg] * rl);
  }
}

// ------------- residual add + LayerNorm (in-place on io) -------------
__global__ __launch_bounds__(256) void add_ln(float* __restrict__ io,
                                              const float* __restrict__ h,
                                              const float* __restrict__ g,
                                              const float* __restrict__ gam,
                                              const float* __restrict__ bet) {
  const size_t row = blockIdx.x;
  float* o = io + row * 1024;
  const float* x = (row < 4096) ? (h + row * 1024) : (g + (row - 4096) * 1024);
  const int t = threadIdx.x;
  float v[4];
  float s1 = 0.f, s2 = 0.f;
#pragma unroll
  for (int k = 0; k < 4; ++k) {
    int idx = t + 256 * k;
    v[k] = o[idx] + x[idx];
    s1 += v[k];
    s2 += v[k] * v[k];
  }
#pragma unroll
  for (int off = 32; off >= 1; off >>= 1) {
    s1 += __shfl_xor(s1, off);
    s2 += __shfl_xor(s2, off);
  }
  __shared__ float r1[4], r2[4];
  if ((t & 63) == 0) { r1[t >> 6] = s1; r2[t >> 6] = s2; }
  __syncthreads();
  s1 = r1[0] + r1[1] + r1[2] + r1[3];
  s2 = r2[0] + r2[1] + r2[2] + r2[3];
  float mean = s1 * (1.f / 1024.f);
  float var = s2 * (1.f / 1024.f) - mean * mean;
  float rstd = rsqrtf(fmaxf(var, 0.f) + 1e-12f);
#pragma unroll
  for (int k = 0; k < 4; ++k) {
    int idx = t + 256 * k;
    o[idx] = (v[k] - mean) * rstd * gam[idx] + bet[idx];
  }
}

extern "C" void kernel_launch(void* const* d_in, const int* in_sizes, int n_in,
                              void* d_out, int out_size, void* d_ws,
                              size_t ws_size, hipStream_t stream) {
  const float* h = (const float*)d_in[0];
  const float* g = (const float*)d_in[1];
  const float* mh = (const float*)d_in[2];
  const float* mg = (const float*)d_in[3];
  const float* r = (const float*)d_in[4];
  const float* seg = (const float*)d_in[5];
  const float* q_w = (const float*)d_in[6];
  const float* k_w = (const float*)d_in[7];
  const float* v_w = (const float*)d_in[8];
  const float* o_w = (const float*)d_in[9];
  const float* r_w = (const float*)d_in[10];
  const float* rrb = (const float*)d_in[11];
  const float* rsb = (const float*)d_in[12];
  const float* rwb = (const float*)d_in[13];
  const float* se = (const float*)d_in[14];
  const float* gam = (const float*)d_in[15];
  const float* bet = (const float*)d_in[16];
  float* out = (float*)d_out;

  // ---- ws layout ----
  char* w = (char*)d_ws;
  __bf16* hgb = (__bf16*)w;                 // 16MB [8192][1024]
  __bf16* vtb = (__bf16*)w;                 // aliases hgb (dead after q-GEMM)
  w += (size_t)16 << 20;
  __bf16* rb = (__bf16*)w;                  // 16MB
  __bf16* avb = (__bf16*)w;                 // aliases rb (dead after r-GEMM)
  w += (size_t)16 << 20;
  __bf16* qwt = (__bf16*)w; w += (size_t)2 << 20;
  __bf16* kwt = (__bf16*)w; w += (size_t)2 << 20;
  __bf16* vwt = (__bf16*)w; w += (size_t)2 << 20;
  __bf16* rwt = (__bf16*)w; w += (size_t)2 << 20;
  __bf16* owt = (__bf16*)w; w += (size_t)2 << 20;
  __bf16* qpb = (__bf16*)w; w += (size_t)16 << 20;  // [8192][1024]
  __bf16* khb = (__bf16*)w; w += (size_t)8 << 20;
  __bf16* vhb = (__bf16*)w; w += (size_t)8 << 20;
  __bf16* krb = (__bf16*)w; w += (size_t)16 << 20;
  unsigned int* mbits = (unsigned int*)w; w += (size_t)1 << 20;
  unsigned char* segvb = (unsigned char*)w; w += 4096;

  dim3 blk(256);

  cvt_bf16_k<<<4096, blk, 0, stream>>>(h, hgb, 4194304);
  cvt_bf16_k<<<4096, blk, 0, stream>>>(g, hgb + 4194304, 4194304);
  cvt_bf16_k<<<8192, blk, 0, stream>>>(r, rb, 8388608);
  cvt_bf16_k<<<1024, blk, 0, stream>>>(o_w, owt, 1048576);
  wtrans_k<<<dim3(16, 16), blk, 0, stream>>>(q_w, qwt);
  wtrans_k<<<dim3(16, 16), blk, 0, stream>>>(k_w, kwt);
  wtrans_k<<<dim3(16, 16), blk, 0, stream>>>(v_w, vwt);
  wtrans_k<<<dim3(16, 16), blk, 0, stream>>>(r_w, rwt);
  packbits_k<<<dim3(16, 64), blk, 0, stream>>>(mh, mg, mbits);
  segv_k<<<16, blk, 0, stream>>>(seg, segvb);

  gemm_mfma<true><<<dim3(8, 32), blk, 0, stream>>>(hgb, kwt, khb);
  gemm_mfma<true><<<dim3(8, 32), blk, 0, stream>>>(hgb, vwt, vhb);
  gemm_mfma<true><<<dim3(8, 64), blk, 0, stream>>>(rb, rwt, krb);
  gemm_mfma<true><<<dim3(8, 64), blk, 0, stream>>>(hgb, qwt, qpb);  // hgb dead after
  vtrans_k<<<dim3(8, 64), blk, 0, stream>>>(vhb, vtb);

  attn6<<<2048, blk, 0, stream>>>(qpb, khb, vtb, krb, mbits, segvb, se, rwb,
                                  rrb, rsb, avb);

  gemm_mfma<false><<<dim3(8, 64), blk, 0, stream>>>(avb, owt, out);
  add_ln<<<8192, blk, 0, stream>>>(out, h, g, gam, bet);
}

// Round 11
// 438.302 us; speedup vs baseline: 2.4954x; 1.5751x over previous
//
#include <hip/hip_runtime.h>
#include <math.h>

#define QS 1024
#define BSZ 4
#define NH 16
#define RL 2048

typedef __attribute__((ext_vector_type(8))) __bf16 bf16x8;
typedef __attribute__((ext_vector_type(16))) float f32x16;
typedef __attribute__((ext_vector_type(4))) float f32x4;

union BV8 { bf16x8 v; uint4 u; __bf16 e[8]; unsigned w[4]; };

// byte offset in a [rows][64 bf16] tile, 128B rows, blk-XOR swizzle
__device__ __forceinline__ int swzb(int row, int blk) {
  return row * 128 + (((blk ^ row) & 7) << 4);
}

typedef __attribute__((address_space(3))) unsigned int lds_u32;
typedef __attribute__((address_space(1))) const unsigned int glb_u32;
__device__ __forceinline__ void gld16(const void* g, void* l) {
  __builtin_amdgcn_global_load_lds((glb_u32*)g, (lds_u32*)l, 16, 0, 0);
}

// ---------------- f32 -> bf16 convert ----------------
__global__ __launch_bounds__(256) void cvt_bf16_k(const float* __restrict__ in,
                                                  __bf16* __restrict__ out, int n) {
  int i = blockIdx.x * 1024 + threadIdx.x * 4;
  if (i + 3 < n) {
    float4 v = *(const float4*)(in + i);
    union { __bf16 b[4]; unsigned long long u; } r;
    r.b[0] = (__bf16)v.x; r.b[1] = (__bf16)v.y;
    r.b[2] = (__bf16)v.z; r.b[3] = (__bf16)v.w;
    *(unsigned long long*)(out + i) = r.u;
  }
}

// ---------------- W[k][n] f32 -> WT[n][k] bf16 ----------------
__global__ __launch_bounds__(256) void wtrans_k(const float* __restrict__ W,
                                                __bf16* __restrict__ WT) {
  __shared__ float tile[64][65];
  int k0 = blockIdx.x * 64, n0 = blockIdx.y * 64;
  int t = threadIdx.x, r = t >> 4, c4 = (t & 15) * 4;
#pragma unroll
  for (int p = 0; p < 4; ++p) {
    float4 v = *(const float4*)(W + (size_t)(k0 + r + 16 * p) * 1024 + n0 + c4);
    *(float4*)&tile[r + 16 * p][c4] = v;
  }
  __syncthreads();
#pragma unroll
  for (int p = 0; p < 4; ++p) {
    int nr = r + 16 * p;
    union { __bf16 b[4]; unsigned long long u; } o;
#pragma unroll
    for (int i = 0; i < 4; ++i) o.b[i] = (__bf16)tile[c4 + i][nr];
    *(unsigned long long*)(WT + (size_t)(n0 + nr) * 1024 + k0 + c4) = o.u;
  }
}

// ------- pack masks to bitfields: mbits[tn(z)][b][j][1024 i-bits] -------
__global__ __launch_bounds__(256) void packbits_k(const float* __restrict__ mh,
                                                  const float* __restrict__ mg,
                                                  unsigned int* __restrict__ mbits) {
  __shared__ unsigned char nib[2][16][64];
  const int t = threadIdx.x;
  const int i0b = blockIdx.x * 64;
  const int jb0 = blockIdx.y * 64;
  const float* srcs[2] = {mh, mg};
#pragma unroll
  for (int tn = 0; tn < 2; ++tn) {
    const float* in = srcs[tn];
#pragma unroll
    for (int p = 0; p < 4; ++p) {
      int item = t + 256 * p;
      int iloc = item >> 4, jbq = item & 15;
      float4 v = *(const float4*)(in + (size_t)(i0b + iloc) * 4096 + jb0 + jbq * 4);
      unsigned char nb = (v.x > 0.5f ? 1 : 0) | (v.y > 0.5f ? 2 : 0) |
                         (v.z > 0.5f ? 4 : 0) | (v.w > 0.5f ? 8 : 0);
      nib[tn][jbq][iloc] = nb;
    }
  }
  __syncthreads();
  {
    int tn = t >> 7, rem = t & 127;
    int jbl = rem >> 1, dw = rem & 1;
    int jbq = jbl >> 2, e = jbl & 3;
    uint4 u0 = *(uint4*)&nib[tn][jbq][32 * dw];
    uint4 u1 = *(uint4*)&nib[tn][jbq][32 * dw + 16];
    unsigned d[8] = {u0.x, u0.y, u0.z, u0.w, u1.x, u1.y, u1.z, u1.w};
    unsigned out = 0;
#pragma unroll
    for (int c = 0; c < 8; ++c) {
      unsigned bits = (d[c] >> e) & 0x01010101u;
      unsigned nv = ((bits * 0x01020408u) >> 24) & 0xFu;
      out |= nv << (4 * c);
    }
    int jb = jb0 + jbl;
    int b = jb & 3, j = jb >> 2;
    mbits[(size_t)(((tn * 4 + b) * 1024 + j)) * 32 + (i0b >> 5) + dw] = out;
  }
}

// ------- segv[b][j] = seg-bit of token j -------
__global__ __launch_bounds__(256) void segv_k(const float* __restrict__ seg,
                                              unsigned char* __restrict__ segv) {
  int id = blockIdx.x * 256 + threadIdx.x;
  if (id < 4096) {
    int b = id >> 10, j = id & 1023;
    segv[b * 1024 + j] = (seg[(size_t)(j * 4 + b) * 2 + 1] > 0.5f) ? 1 : 0;
  }
}

// ---------------- bf16 MFMA GEMM: C[M][1024] = A[M][1024] * BT^T ----------------
template <bool OUT_BF16>
__global__ __launch_bounds__(256) void gemm_mfma(const __bf16* __restrict__ A,
                                                 const __bf16* __restrict__ BT,
                                                 void* __restrict__ Cout) {
  alignas(16) __shared__ __bf16 sA[128 * 64];
  alignas(16) __shared__ __bf16 sB[128 * 64];
  const int t = threadIdx.x;
  const int lane = t & 63, wave = t >> 6;
  // XCD remap: each XCD owns a contiguous M-stripe across all N (A fetched once)
  const int lin = blockIdx.y * 8 + blockIdx.x;
  const int xcd = lin & 7, l = lin >> 3;
  const int n0 = (l & 7) * 128;
  const size_t m0 = (size_t)(xcd * (gridDim.y >> 3) + (l >> 3)) * 128;
  const int wm = (wave >> 1) * 64, wn = (wave & 1) * 64;

  f32x16 acc[2][2];
#pragma unroll
  for (int a = 0; a < 2; ++a)
#pragma unroll
    for (int b = 0; b < 2; ++b)
#pragma unroll
      for (int i = 0; i < 16; ++i) acc[a][b][i] = 0.f;

  for (int k0 = 0; k0 < 1024; k0 += 64) {
    __syncthreads();
#pragma unroll
    for (int p = 0; p < 4; ++p) {
      int idx = t + 256 * p;
      int row = idx >> 3, blk = idx & 7;
      int sblk = (blk ^ (row & 7)) * 8;
      gld16(A + (m0 + row) * 1024 + k0 + sblk, (char*)sA + idx * 16);
      gld16(BT + (size_t)(n0 + row) * 1024 + k0 + sblk, (char*)sB + idx * 16);
    }
    __syncthreads();
#pragma unroll
    for (int kk = 0; kk < 4; ++kk) {
      int blk = 2 * kk + (lane >> 5);
      bf16x8 af[2], bfr[2];
#pragma unroll
      for (int mi = 0; mi < 2; ++mi)
        af[mi] = *(bf16x8*)((char*)sA + swzb(wm + mi * 32 + (lane & 31), blk));
#pragma unroll
      for (int ni = 0; ni < 2; ++ni)
        bfr[ni] = *(bf16x8*)((char*)sB + swzb(wn + ni * 32 + (lane & 31), blk));
#pragma unroll
      for (int mi = 0; mi < 2; ++mi)
#pragma unroll
        for (int ni = 0; ni < 2; ++ni)
          acc[mi][ni] = __builtin_amdgcn_mfma_f32_32x32x16_bf16(
              af[mi], bfr[ni], acc[mi][ni], 0, 0, 0);
    }
  }
#pragma unroll
  for (int mi = 0; mi < 2; ++mi)
#pragma unroll
    for (int ni = 0; ni < 2; ++ni)
#pragma unroll
      for (int rg = 0; rg < 16; ++rg) {
        int row = wm + mi * 32 + (rg & 3) + 8 * (rg >> 2) + 4 * (lane >> 5);
        int col = wn + ni * 32 + (lane & 31);
        float v = acc[mi][ni][rg];
        if (OUT_BF16)
          ((__bf16*)Cout)[(m0 + row) * 1024 + n0 + col] = (__bf16)v;
        else
          ((float*)Cout)[(m0 + row) * 1024 + n0 + col] = v;
      }
}

// ---------------- V transpose: vhb [tok][(b,n,d)] -> vtb [(b,n,d)][tok] ----------------
__global__ __launch_bounds__(256) void vtrans_k(const __bf16* __restrict__ vhb,
                                                __bf16* __restrict__ vtb) {
  alignas(16) __shared__ __bf16 st[64 * 128];
  const int t = threadIdx.x;
  const int tok0 = blockIdx.x * 128;
  const int bn = blockIdx.y;
  const int b = bn >> 4, n = bn & 15;
#pragma unroll
  for (int p = 0; p < 4; ++p) {
    int item = t + 256 * p;
    int tok = item >> 3, c8 = item & 7;
    BV8 v;
    v.u = *(const uint4*)(vhb + ((size_t)((tok0 + tok) * 4 + b)) * 1024 + n * 64 + c8 * 8);
#pragma unroll
    for (int e = 0; e < 8; ++e) {
      int d = c8 * 8 + e;
      *(__bf16*)((char*)st + d * 256 + ((2 * tok) ^ (((d >> 3) & 7) << 4))) = v.e[e];
    }
  }
  __syncthreads();
#pragma unroll
  for (int p = 0; p < 4; ++p) {
    int item = t + 256 * p;
    int d = item >> 4, tc = (item & 15) * 8;
    uint4 v = *(uint4*)((char*)st + d * 256 + ((2 * tc) ^ (((d >> 3) & 7) << 4)));
    *(uint4*)(vtb + ((size_t)(bn * 64 + d)) * 1024 + tok0 + tc) = v;
  }
}

// ------- fused relative attention v7: attn6 structure, no-spill bounds, L2-friendly decode -------
__global__ __launch_bounds__(256, 2) void attn7(
    const __bf16* __restrict__ qpb, const __bf16* __restrict__ kb,
    const __bf16* __restrict__ vtb, const __bf16* __restrict__ krb,
    const unsigned int* __restrict__ mbits, const unsigned char* __restrict__ segv,
    const float* __restrict__ se, const float* __restrict__ rwb,
    const float* __restrict__ rrb, const float* __restrict__ rsb,
    __bf16* __restrict__ av) {
  const int t = threadIdx.x;
  const int lane = t & 63, wave = t >> 6;
  const int hlf = lane >> 5, ln31 = lane & 31;
  const int qh = wave >> 1, kh = wave & 1;

  // XCD-aware decode: i0 fastest within an XCD, then head, then z.
  // Resident blocks on an XCD concentrate on ~1 head -> K/V/Kr stay L2-hot.
  const int bid = blockIdx.x;
  const int xcd = bid & 7, idx0 = bid >> 3;
  const int i0 = (idx0 & 15) * 64;
  const int bn = xcd * 8 + ((idx0 >> 4) & 7);
  const int z = idx0 >> 7;
  const int b = bn >> 4, n = bn & 15;

  alignas(16) __shared__ __bf16 sp[2][2][32 * 64];  // 16KB P double-buffered
  __shared__ float sl[4][2][16];

  // ---- Q fragments (+biases), alpha/beta for segment fold ----
  const size_t qbase =
      ((size_t)((z * 1024 + i0 + 32 * qh + ln31) * 4 + b)) * 1024 + n * 64;
  bf16x8 qw[4], qr[4];
  float e0 = 0.f, e1 = 0.f;
#pragma unroll
  for (int kk = 0; kk < 4; ++kk) {
    BV8 raw;
    raw.u = *(const uint4*)(qpb + qbase + 16 * kk + 8 * hlf);
    int d0 = 16 * kk + 8 * hlf;
    float4 w0 = *(const float4*)(rwb + n * 64 + d0);
    float4 w1 = *(const float4*)(rwb + n * 64 + d0 + 4);
    float4 r0 = *(const float4*)(rrb + n * 64 + d0);
    float4 r1 = *(const float4*)(rrb + n * 64 + d0 + 4);
    float4 sb0 = *(const float4*)(rsb + n * 64 + d0);
    float4 sb1 = *(const float4*)(rsb + n * 64 + d0 + 4);
    float4 ea0 = *(const float4*)(se + n * 64 + d0);
    float4 ea1 = *(const float4*)(se + n * 64 + d0 + 4);
    float4 eb0 = *(const float4*)(se + 1024 + n * 64 + d0);
    float4 eb1 = *(const float4*)(se + 1024 + n * 64 + d0 + 4);
    float wv[8] = {w0.x, w0.y, w0.z, w0.w, w1.x, w1.y, w1.z, w1.w};
    float rv[8] = {r0.x, r0.y, r0.z, r0.w, r1.x, r1.y, r1.z, r1.w};
    float sv_[8] = {sb0.x, sb0.y, sb0.z, sb0.w, sb1.x, sb1.y, sb1.z, sb1.w};
    float ev0[8] = {ea0.x, ea0.y, ea0.z, ea0.w, ea1.x, ea1.y, ea1.z, ea1.w};
    float ev1[8] = {eb0.x, eb0.y, eb0.z, eb0.w, eb1.x, eb1.y, eb1.z, eb1.w};
    BV8 qwv, qrv;
#pragma unroll
    for (int i = 0; i < 8; ++i) {
      float f = (float)raw.e[i];
      qwv.e[i] = (__bf16)(f + wv[i]);
      qrv.e[i] = (__bf16)(f + rv[i]);
      float fs = f + sv_[i];
      e0 += fs * ev0[i];
      e1 += fs * ev1[i];
    }
    qw[kk] = qwv.v;
    qr[kk] = qrv.v;
  }
  e0 += __shfl_xor(e0, 32);
  e1 += __shfl_xor(e1, 32);
  float si = (float)segv[b * 1024 + i0 + 32 * qh + ln31];
  float alpha = e0 + (e1 - e0) * si;
  float beta = (e1 - e0) * (1.f - 2.f * si);
  bf16x8 augA;
  {
    BV8 aa;
    aa.w[0] = aa.w[1] = aa.w[2] = aa.w[3] = 0;
    if (!hlf) {
      union { __bf16 b2[2]; unsigned u; } w2;
      w2.b2[0] = (__bf16)alpha;
      w2.b2[1] = (__bf16)beta;
      aa.w[0] = w2.u;
    }
    augA = aa.v;
  }

  f32x16 oacc, colsum;
#pragma unroll
  for (int i = 0; i < 16; ++i) { oacc[i] = 0.f; colsum[i] = 0.f; }

  const unsigned char* segp = segv + b * 1024;
  const __bf16* kbase =
      kb + ((size_t)((32 * kh + ln31) * 4 + b)) * 1024 + n * 64 + 8 * hlf;
  const __bf16* vbase =
      vtb + ((size_t)(bn * 64 + 32 * kh + ln31)) * 1024 + 8 * hlf;
  const __bf16* krbB = krb + (size_t)b * 1024 + n * 64 + 8 * hlf;
  const size_t mbase =
      (size_t)((z * 4 + b) * 1024 + 32 * kh + ln31) * 32 + (i0 >> 5) + qh;
  // BD window base row for this wave (tile tt adds 32*tt)
  const int wrow0 = 32 * (kh - qh) + 993 - i0 + ln31;

  for (int jt = 0; jt < 16; ++jt) {
    const int J0 = 64 * jt;
    // ---- (A) mask + seg + augB ----
    unsigned praw = mbits[mbase + (size_t)J0 * 32];
    unsigned sj = segp[J0 + 32 * kh + ln31];
    bf16x8 augB;
    {
      BV8 bb2;
      bb2.w[0] = hlf ? 0u : (0x3F80u | (sj * 0x3F800000u));
      bb2.w[1] = bb2.w[2] = bb2.w[3] = 0;
      augB = bb2.v;
    }

    // ---- (B) AC: kf transient ----
    f32x16 ac;
#pragma unroll
    for (int i = 0; i < 16; ++i) ac[i] = 0.f;
    {
      bf16x8 kf[4];
#pragma unroll
      for (int kk = 0; kk < 4; ++kk)
        kf[kk] = *(const bf16x8*)(kbase + (size_t)J0 * 4096 + 16 * kk);
      __builtin_amdgcn_s_setprio(1);
#pragma unroll
      for (int kk = 0; kk < 4; ++kk)
        ac = __builtin_amdgcn_mfma_f32_32x32x16_bf16(qw[kk], kf[kk], ac, 0, 0, 0);
      ac = __builtin_amdgcn_mfma_f32_32x32x16_bf16(augA, augB, ac, 0, 0, 0);
      __builtin_amdgcn_s_setprio(0);
    }

    // ---- (C) BD: direct global Kr, per-tile transient fragments ----
    f32x16 bd[2];
#pragma unroll
    for (int tt = 0; tt < 2; ++tt) {
#pragma unroll
      for (int i = 0; i < 16; ++i) bd[tt][i] = 0.f;
      int w = min(J0 + wrow0 + 32 * tt, 2047);
      const __bf16* krp = krbB + (size_t)w * 4096;
      bf16x8 krf[4];
#pragma unroll
      for (int kk = 0; kk < 4; ++kk)
        krf[kk] = *(const bf16x8*)(krp + 16 * kk);
      __builtin_amdgcn_s_setprio(1);
#pragma unroll
      for (int kk = 0; kk < 4; ++kk)
        bd[tt] = __builtin_amdgcn_mfma_f32_32x32x16_bf16(qr[kk], krf[kk], bd[tt], 0, 0, 0);
      __builtin_amdgcn_s_setprio(0);
    }

    // ---- (D) V frags: issued now, consumed after the barrier ----
    bf16x8 vf[4];
#pragma unroll
    for (int kk = 0; kk < 4; ++kk)
      vf[kk] = *(const bf16x8*)(vbase + J0 + 16 * kk);

    // ---- (E) realign BD + score + P write (buffer jt&1) ----
    char* spw = (char*)&sp[jt & 1][qh][0];
#pragma unroll
    for (int rg = 0; rg < 16; ++rg) {
      int q_ = (rg & 3) + 8 * (rg >> 2) + 4 * hlf;
      int jsrc = (ln31 + q_ + 1) & 31;
      float selv = (jsrc > q_) ? bd[1][rg] : bd[0][rg];
      int addr = ((lane & 32) | ((ln31 + 31 - q_) & 31)) << 2;
      float bdr = __int_as_float(
          __builtin_amdgcn_ds_bpermute(addr, __float_as_int(selv)));
      float s = (ac[rg] + bdr) * 0.18033688f;  // 0.125*log2(e)
      float p = __builtin_amdgcn_exp2f(s);
      int sh = (rg & 3) + 8 * (rg >> 2);
      p = ((praw >> (hlf * 4 + sh)) & 1) ? 0.f : p;
      colsum[rg] += p;
      *(__bf16*)(spw + q_ * 128 + ((2 * (32 * kh + ln31)) ^ ((q_ & 7) << 4))) =
          (__bf16)p;
    }

    // ---- (F) barrier: LDS-only wait; vf rides across in flight ----
    asm volatile("s_waitcnt lgkmcnt(0)\n\ts_barrier" ::: "memory");
    __builtin_amdgcn_sched_barrier(0);

    // ---- (G) PV ----
    __builtin_amdgcn_s_setprio(1);
#pragma unroll
    for (int kk = 0; kk < 4; ++kk) {
      bf16x8 pa = *(const bf16x8*)(
          spw + ln31 * 128 + ((32 * kk + 16 * hlf) ^ ((ln31 & 7) << 4)));
      oacc = __builtin_amdgcn_mfma_f32_32x32x16_bf16(pa, vf[kk], oacc, 0, 0, 0);
    }
    __builtin_amdgcn_s_setprio(0);
  }

  // ---- epilogue: l reduce + merge + scale + store ----
#pragma unroll
  for (int m = 1; m <= 16; m <<= 1)
#pragma unroll
    for (int rg = 0; rg < 16; ++rg) colsum[rg] += __shfl_xor(colsum[rg], m);
  __syncthreads();
  if (ln31 == 0) {
#pragma unroll
    for (int rg = 0; rg < 16; ++rg) sl[wave][hlf][rg] = colsum[rg];
  }
  __syncthreads();
#pragma unroll
  for (int rg = 0; rg < 16; ++rg) {
    float l = sl[2 * qh][hlf][rg] + sl[2 * qh + 1][hlf][rg];
    float rl = __fdividef(1.f, l);
    int qrow = 32 * qh + (rg & 3) + 8 * (rg >> 2) + 4 * hlf;
    av[((size_t)((z * 1024 + i0 + qrow) * 4 + b)) * 1024 + n * 64 + 32 * kh + ln31] =
        (__bf16)(oacc[rg] * rl);
  }
}

// ------------- residual add + LayerNorm (in-place on io) -------------
__global__ __launch_bounds__(256) void add_ln(float* __restrict__ io,
                                              const float* __restrict__ h,
                                              const float* __restrict__ g,
                                              const float* __restrict__ gam,
                                              const float* __restrict__ bet) {
  const size_t row = blockIdx.x;
  float* o = io + row * 1024;
  const float* x = (row < 4096) ? (h + row * 1024) : (g + (row - 4096) * 1024);
  const int t = threadIdx.x;
  float v[4];
  float s1 = 0.f, s2 = 0.f;
#pragma unroll
  for (int k = 0; k < 4; ++k) {
    int idx = t + 256 * k;
    v[k] = o[idx] + x[idx];
    s1 += v[k];
    s2 += v[k] * v[k];
  }
#pragma unroll
  for (int off = 32; off >= 1; off >>= 1) {
    s1 += __shfl_xor(s1, off);
    s2 += __shfl_xor(s2, off);
  }
  __shared__ float r1[4], r2[4];
  if ((t & 63) == 0) { r1[t >> 6] = s1; r2[t >> 6] = s2; }
  __syncthreads();
  s1 = r1[0] + r1[1] + r1[2] + r1[3];
  s2 = r2[0] + r2[1] + r2[2] + r2[3];
  float mean = s1 * (1.f / 1024.f);
  float var = s2 * (1.f / 1024.f) - mean * mean;
  float rstd = rsqrtf(fmaxf(var, 0.f) + 1e-12f);
#pragma unroll
  for (int k = 0; k < 4; ++k) {
    int idx = t + 256 * k;
    o[idx] = (v[k] - mean) * rstd * gam[idx] + bet[idx];
  }
}

extern "C" void kernel_launch(void* const* d_in, const int* in_sizes, int n_in,
                              void* d_out, int out_size, void* d_ws,
                              size_t ws_size, hipStream_t stream) {
  const float* h = (const float*)d_in[0];
  const float* g = (const float*)d_in[1];
  const float* mh = (const float*)d_in[2];
  const float* mg = (const float*)d_in[3];
  const float* r = (const float*)d_in[4];
  const float* seg = (const float*)d_in[5];
  const float* q_w = (const float*)d_in[6];
  const float* k_w = (const float*)d_in[7];
  const float* v_w = (const float*)d_in[8];
  const float* o_w = (const float*)d_in[9];
  const float* r_w = (const float*)d_in[10];
  const float* rrb = (const float*)d_in[11];
  const float* rsb = (const float*)d_in[12];
  const float* rwb = (const float*)d_in[13];
  const float* se = (const float*)d_in[14];
  const float* gam = (const float*)d_in[15];
  const float* bet = (const float*)d_in[16];
  float* out = (float*)d_out;

  // ---- ws layout ----
  char* w = (char*)d_ws;
  __bf16* hgb = (__bf16*)w;                 // 16MB [8192][1024]
  __bf16* vtb = (__bf16*)w;                 // aliases hgb (dead after q-GEMM)
  w += (size_t)16 << 20;
  __bf16* rb = (__bf16*)w;                  // 16MB
  __bf16* avb = (__bf16*)w;                 // aliases rb (dead after r-GEMM)
  w += (size_t)16 << 20;
  __bf16* qwt = (__bf16*)w; w += (size_t)2 << 20;
  __bf16* kwt = (__bf16*)w; w += (size_t)2 << 20;
  __bf16* vwt = (__bf16*)w; w += (size_t)2 << 20;
  __bf16* rwt = (__bf16*)w; w += (size_t)2 << 20;
  __bf16* owt = (__bf16*)w; w += (size_t)2 << 20;
  __bf16* qpb = (__bf16*)w; w += (size_t)16 << 20;  // [8192][1024]
  __bf16* khb = (__bf16*)w; w += (size_t)8 << 20;
  __bf16* vhb = (__bf16*)w; w += (size_t)8 << 20;
  __bf16* krb = (__bf16*)w; w += (size_t)16 << 20;
  unsigned int* mbits = (unsigned int*)w; w += (size_t)1 << 20;
  unsigned char* segvb = (unsigned char*)w; w += 4096;

  dim3 blk(256);

  cvt_bf16_k<<<4096, blk, 0, stream>>>(h, hgb, 4194304);
  cvt_bf16_k<<<4096, blk, 0, stream>>>(g, hgb + 4194304, 4194304);
  cvt_bf16_k<<<8192, blk, 0, stream>>>(r, rb, 8388608);
  cvt_bf16_k<<<1024, blk, 0, stream>>>(o_w, owt, 1048576);
  wtrans_k<<<dim3(16, 16), blk, 0, stream>>>(q_w, qwt);
  wtrans_k<<<dim3(16, 16), blk, 0, stream>>>(k_w, kwt);
  wtrans_k<<<dim3(16, 16), blk, 0, stream>>>(v_w, vwt);
  wtrans_k<<<dim3(16, 16), blk, 0, stream>>>(r_w, rwt);
  packbits_k<<<dim3(16, 64), blk, 0, stream>>>(mh, mg, mbits);
  segv_k<<<16, blk, 0, stream>>>(seg, segvb);

  gemm_mfma<true><<<dim3(8, 32), blk, 0, stream>>>(hgb, kwt, khb);
  gemm_mfma<true><<<dim3(8, 32), blk, 0, stream>>>(hgb, vwt, vhb);
  gemm_mfma<true><<<dim3(8, 64), blk, 0, stream>>>(rb, rwt, krb);
  gemm_mfma<true><<<dim3(8, 64), blk, 0, stream>>>(hgb, qwt, qpb);  // hgb dead after
  vtrans_k<<<dim3(8, 64), blk, 0, stream>>>(vhb, vtb);

  attn7<<<2048, blk, 0, stream>>>(qpb, khb, vtb, krb, mbits, segvb, se, rwb,
                                  rrb, rsb, avb);

  gemm_mfma<false><<<dim3(8, 64), blk, 0, stream>>>(avb, owt, out);
  add_ln<<<8192, blk, 0, stream>>>(out, h, g, gam, bet);
}